// Round 1
// baseline (594.876 us; speedup 1.0000x reference)
//
#include <hip/hip_runtime.h>
#include <hip/hip_bf16.h>

#define EXPERTS 8
#define TOK 2048
#define DM 1024
#define DH 4096

#define BM 128
#define BN 128
#define BK 32
#define LSTR 40   // padded LDS row stride in bf16 elems (80 B -> 20 banks, 2-way max)

typedef __bf16 bf16x8 __attribute__((ext_vector_type(8)));
typedef float  f32x4  __attribute__((ext_vector_type(4)));

static __device__ __forceinline__ bf16x8 cvt8(float4 a, float4 b) {
    bf16x8 r;
    r[0] = (__bf16)a.x; r[1] = (__bf16)a.y; r[2] = (__bf16)a.z; r[3] = (__bf16)a.w;
    r[4] = (__bf16)b.x; r[5] = (__bf16)b.y; r[6] = (__bf16)b.z; r[7] = (__bf16)b.w;
    return r;
}

// C = A * B^T  (A: M x K row-major, B: N x K row-major, C: M x N row-major)
// A is fp32 (converted inline) or bf16; B always fp32 converted inline.
// Optional ReLU on output; output bf16 or fp32.
template<bool A_F32, bool RELU, bool OUT_BF16>
__global__ __launch_bounds__(256, 2)
void gemm_bt(const void* __restrict__ Ap, const float* __restrict__ Bp,
             void* __restrict__ Cp,
             int N, int K, int tiles_m, int tiles_n,
             size_t sA, size_t sB, size_t sC)
{
    __shared__ __bf16 As[BM * LSTR];
    __shared__ __bf16 Bs[BN * LSTR];

    const int bid   = blockIdx.x;
    const int per_e = tiles_m * tiles_n;
    const int e  = bid / per_e;
    const int t  = bid % per_e;
    const int tn = t / tiles_m;   // consecutive blocks share the B panel
    const int tm = t % tiles_m;

    const int tid  = threadIdx.x;
    const int srow = tid >> 1;          // 0..127 staging row
    const int scol = (tid & 1) << 4;    // 0 or 16 (elements within BK=32)

    const float*  pAf = nullptr;
    const __bf16* pAh = nullptr;
    if constexpr (A_F32)
        pAf = (const float*)Ap + e * sA + (size_t)(tm * BM + srow) * K + scol;
    else
        pAh = (const __bf16*)Ap + e * sA + (size_t)(tm * BM + srow) * K + scol;
    const float* pBf = Bp + e * sB + (size_t)(tn * BN + srow) * K + scol;

    float4 A0, A1, A2, A3;
    int4   H0, H1;
    float4 B0, B1, B2, B3;

    if constexpr (A_F32) {
        A0 = *(const float4*)(pAf);      A1 = *(const float4*)(pAf + 4);
        A2 = *(const float4*)(pAf + 8);  A3 = *(const float4*)(pAf + 12);
    } else {
        H0 = *(const int4*)(pAh);        H1 = *(const int4*)(pAh + 8);
    }
    B0 = *(const float4*)(pBf);      B1 = *(const float4*)(pBf + 4);
    B2 = *(const float4*)(pBf + 8);  B3 = *(const float4*)(pBf + 12);

    const int l   = tid & 63;
    const int wid = tid >> 6;     // 0..3
    const int wr  = wid >> 1, wc = wid & 1;
    const int lr  = l & 15;       // fragment row/col
    const int kg  = l >> 4;       // k-group 0..3 (8 bf16 each)

    const __bf16* aRd = &As[(wr * 64 + lr) * LSTR + kg * 8];
    const __bf16* bRd = &Bs[(wc * 64 + lr) * LSTR + kg * 8];
    __bf16* aWr = &As[srow * LSTR + scol];
    __bf16* bWr = &Bs[srow * LSTR + scol];

    f32x4 acc[4][4];
    #pragma unroll
    for (int m = 0; m < 4; ++m)
        #pragma unroll
        for (int n = 0; n < 4; ++n)
            acc[m][n] = (f32x4){0.f, 0.f, 0.f, 0.f};

    const int NT = K / BK;
    for (int kt = 0; kt < NT; ++kt) {
        __syncthreads();   // previous compute done; LDS free to overwrite
        if constexpr (A_F32) {
            *(bf16x8*)(aWr)     = cvt8(A0, A1);
            *(bf16x8*)(aWr + 8) = cvt8(A2, A3);
        } else {
            *(int4*)(aWr)       = H0;
            *(int4*)(aWr + 8)   = H1;
        }
        *(bf16x8*)(bWr)     = cvt8(B0, B1);
        *(bf16x8*)(bWr + 8) = cvt8(B2, B3);
        __syncthreads();   // tile staged

        if (kt + 1 < NT) { // prefetch next tile into regs; latency hides under MFMA
            if constexpr (A_F32) {
                pAf += BK;
                A0 = *(const float4*)(pAf);      A1 = *(const float4*)(pAf + 4);
                A2 = *(const float4*)(pAf + 8);  A3 = *(const float4*)(pAf + 12);
            } else {
                pAh += BK;
                H0 = *(const int4*)(pAh);        H1 = *(const int4*)(pAh + 8);
            }
            pBf += BK;
            B0 = *(const float4*)(pBf);      B1 = *(const float4*)(pBf + 4);
            B2 = *(const float4*)(pBf + 8);  B3 = *(const float4*)(pBf + 12);
        }

        bf16x8 af[4], bfr[4];
        #pragma unroll
        for (int m = 0; m < 4; ++m) af[m]  = *(const bf16x8*)(aRd + m * 16 * LSTR);
        #pragma unroll
        for (int n = 0; n < 4; ++n) bfr[n] = *(const bf16x8*)(bRd + n * 16 * LSTR);
        #pragma unroll
        for (int m = 0; m < 4; ++m)
            #pragma unroll
            for (int n = 0; n < 4; ++n)
                acc[m][n] = __builtin_amdgcn_mfma_f32_16x16x32_bf16(af[m], bfr[n], acc[m][n], 0, 0, 0);
    }

    // Epilogue. C/D layout (verified m89/m91): col = lane&15, row = (lane>>4)*4 + reg
    const int orow = tm * BM + wr * 64 + kg * 4;
    const int ocol = tn * BN + wc * 64 + lr;
    if constexpr (OUT_BF16) {
        __bf16* C = (__bf16*)Cp + e * sC;
        #pragma unroll
        for (int m = 0; m < 4; ++m)
            #pragma unroll
            for (int j = 0; j < 4; ++j) {
                const size_t base = (size_t)(orow + m * 16 + j) * N + ocol;
                #pragma unroll
                for (int n = 0; n < 4; ++n) {
                    float v = acc[m][n][j];
                    if (RELU) v = fmaxf(v, 0.f);
                    C[base + n * 16] = (__bf16)v;
                }
            }
    } else {
        float* C = (float*)Cp + e * sC;
        #pragma unroll
        for (int m = 0; m < 4; ++m)
            #pragma unroll
            for (int j = 0; j < 4; ++j) {
                const size_t base = (size_t)(orow + m * 16 + j) * N + ocol;
                #pragma unroll
                for (int n = 0; n < 4; ++n) {
                    float v = acc[m][n][j];
                    if (RELU) v = fmaxf(v, 0.f);
                    C[base + n * 16] = v;
                }
            }
    }
}

static inline size_t zmin(size_t a, size_t b) { return a < b ? a : b; }

extern "C" void kernel_launch(void* const* d_in, const int* in_sizes, int n_in,
                              void* d_out, int out_size, void* d_ws, size_t ws_size,
                              hipStream_t stream) {
    const float* x  = (const float*)d_in[0];   // [8, 2048, 1024]
    const float* w1 = (const float*)d_in[1];   // [8, 4096, 1024]
    const float* w2 = (const float*)d_in[2];   // [8, 1024, 4096]
    float* out = (float*)d_out;                // [8, 2048, 1024]
    __bf16* ffn1 = (__bf16*)d_ws;              // bf16 intermediate

    const size_t per_e = (size_t)TOK * DH * sizeof(__bf16);  // 16.8 MB / expert

    if (ws_size >= per_e) {
        int epg = (int)zmin((size_t)EXPERTS, ws_size / per_e);  // experts per group
        for (int e0 = 0; e0 < EXPERTS; e0 += epg) {
            int g = (EXPERTS - e0 < epg) ? (EXPERTS - e0) : epg;
            // GEMM1 + ReLU: [g] x (2048x1024) * (4096x1024)^T -> bf16 ws
            dim3 grid1(g * (TOK / BM) * (DH / BN));
            hipLaunchKernelGGL((gemm_bt<true, true, true>), grid1, dim3(256), 0, stream,
                x + (size_t)e0 * TOK * DM, w1 + (size_t)e0 * DH * DM, ffn1,
                DH, DM, TOK / BM, DH / BN,
                (size_t)TOK * DM, (size_t)DH * DM, (size_t)TOK * DH);
            // GEMM2: [g] x (2048x4096 bf16) * (1024x4096)^T -> fp32 out
            dim3 grid2(g * (TOK / BM) * (DM / BN));
            hipLaunchKernelGGL((gemm_bt<false, false, false>), grid2, dim3(256), 0, stream,
                ffn1, w2 + (size_t)e0 * DM * DH, out + (size_t)e0 * TOK * DM,
                DM, DH, TOK / BM, DM / BN,
                (size_t)TOK * DH, (size_t)DM * DH, (size_t)TOK * DM);
        }
    } else {
        // Tiny workspace fallback: chunk token rows within each expert.
        int rows = (int)((ws_size / ((size_t)DH * sizeof(__bf16))) / BM) * BM;
        if (rows <= 0) rows = BM;            // best effort
        if (rows > TOK) rows = TOK;
        for (int e = 0; e < EXPERTS; ++e) {
            for (int r0 = 0; r0 < TOK; r0 += rows) {
                int mr = (TOK - r0 < rows) ? (TOK - r0) : rows;
                dim3 grid1((mr / BM) * (DH / BN));
                hipLaunchKernelGGL((gemm_bt<true, true, true>), grid1, dim3(256), 0, stream,
                    x + ((size_t)e * TOK + r0) * DM, w1 + (size_t)e * DH * DM, ffn1,
                    DH, DM, mr / BM, DH / BN, (size_t)0, (size_t)0, (size_t)0);
                dim3 grid2((mr / BM) * (DM / BN));
                hipLaunchKernelGGL((gemm_bt<false, false, false>), grid2, dim3(256), 0, stream,
                    ffn1, w2 + (size_t)e * DM * DH, out + ((size_t)e * TOK + r0) * DM,
                    DM, DH, mr / BM, DM / BN, (size_t)0, (size_t)0, (size_t)0);
            }
        }
    }
}

// Round 2
// 452.184 us; speedup vs baseline: 1.3156x; 1.3156x over previous
//
#include <hip/hip_runtime.h>
#include <hip/hip_bf16.h>

#define EXPERTS 8
#define TOK 2048
#define DM 1024
#define DH 4096

#define BM 128
#define BN 128
#define BK 32
#define LSTR 40   // padded LDS stride for reg-staged paths

typedef __bf16 bf16x8 __attribute__((ext_vector_type(8)));
typedef float  f32x4  __attribute__((ext_vector_type(4)));

static __device__ __forceinline__ bf16x8 cvt8(float4 a, float4 b) {
    bf16x8 r;
    r[0] = (__bf16)a.x; r[1] = (__bf16)a.y; r[2] = (__bf16)a.z; r[3] = (__bf16)a.w;
    r[4] = (__bf16)b.x; r[5] = (__bf16)b.y; r[6] = (__bf16)b.z; r[7] = (__bf16)b.w;
    return r;
}

// async global->LDS, 16B per lane, dest = wave-uniform base + lane*16
static __device__ __forceinline__ void gload16(const __bf16* g, __bf16* l) {
    __builtin_amdgcn_global_load_lds(
        (__attribute__((address_space(1))) void*)g,
        (__attribute__((address_space(3))) void*)l, 16, 0, 0);
}

// fp32 -> bf16 bulk convert, 8 elems/thread/iter, fully coalesced
__global__ __launch_bounds__(256)
void cvt_bf16(const float* __restrict__ in, __bf16* __restrict__ out, int n8) {
    int i = blockIdx.x * blockDim.x + threadIdx.x;
    const int stride = gridDim.x * blockDim.x;
    for (; i < n8; i += stride) {
        const float4* p = (const float4*)in + (size_t)i * 2;
        float4 a = p[0], b = p[1];
        *((bf16x8*)out + i) = cvt8(a, b);
    }
}

// C = A * B^T. AMODE/BMODE: 0 = bf16 via global_load_lds (linear LDS [128][32]),
//                           2 = fp32 reg-staged + inline cvt (padded LDS [128][40])
template<int AMODE, int BMODE, bool RELU, bool OUT_BF16>
__global__ __launch_bounds__(256)
void gemm2(const void* __restrict__ Ap, const void* __restrict__ Bp,
           void* __restrict__ Cp, int N, int K, int tiles_m, int tiles_n,
           size_t sA, size_t sB, size_t sC)
{
    constexpr int LA = (AMODE == 0) ? BK : LSTR;
    constexpr int LB = (BMODE == 0) ? BK : LSTR;
    __shared__ __bf16 As[BM * LA];
    __shared__ __bf16 Bs[BN * LB];

    // XCD-aware bijective swizzle (grid % 8 == 0 for all our launches)
    int bid = blockIdx.x;
    const int chunk = gridDim.x >> 3;
    bid = (bid & 7) * chunk + (bid >> 3);

    const int per_e = tiles_m * tiles_n;
    const int e  = bid / per_e;
    const int t  = bid - e * per_e;
    const int tn = t / tiles_m;   // consecutive tiles share the B panel
    const int tm = t - tn * tiles_m;

    const int tid = threadIdx.x;
    const int l   = tid & 63;
    const int wid = tid >> 6;
    const int wr  = wid >> 1, wc = wid & 1;
    const int lr  = l & 15;
    const int kg  = l >> 4;
    const int srow = tid >> 1;
    const int scol = (tid & 1) << 4;

    // ---- A staging setup ----
    const __bf16* gA = nullptr; __bf16* lA = nullptr;
    const float*  pAf = nullptr; __bf16* aWr = nullptr;
    float4 A0, A1, A2, A3;
    if constexpr (AMODE == 0) {
        gA = (const __bf16*)Ap + e * sA
           + (size_t)(tm * BM + wid * 16 + (l >> 2)) * K + (l & 3) * 8;
        lA = As + wid * 512;   // wave-uniform; HW adds lane*16B
    } else {
        pAf = (const float*)Ap + e * sA + (size_t)(tm * BM + srow) * K + scol;
        aWr = As + srow * LA + scol;
        A0 = *(const float4*)(pAf);      A1 = *(const float4*)(pAf + 4);
        A2 = *(const float4*)(pAf + 8);  A3 = *(const float4*)(pAf + 12);
    }
    // ---- B staging setup ----
    const __bf16* gB = nullptr; __bf16* lB = nullptr;
    const float*  pBf = nullptr; __bf16* bWr = nullptr;
    float4 B0, B1, B2, B3;
    if constexpr (BMODE == 0) {
        gB = (const __bf16*)Bp + e * sB
           + (size_t)(tn * BN + wid * 16 + (l >> 2)) * K + (l & 3) * 8;
        lB = Bs + wid * 512;
    } else {
        pBf = (const float*)Bp + e * sB + (size_t)(tn * BN + srow) * K + scol;
        bWr = Bs + srow * LB + scol;
        B0 = *(const float4*)(pBf);      B1 = *(const float4*)(pBf + 4);
        B2 = *(const float4*)(pBf + 8);  B3 = *(const float4*)(pBf + 12);
    }

    const __bf16* aRd = As + (wr * 64 + lr) * LA + kg * 8;
    const __bf16* bRd = Bs + (wc * 64 + lr) * LB + kg * 8;

    f32x4 acc[4][4];
    #pragma unroll
    for (int m = 0; m < 4; ++m)
        #pragma unroll
        for (int n = 0; n < 4; ++n)
            acc[m][n] = (f32x4){0.f, 0.f, 0.f, 0.f};

    const int NT = K / BK;
    for (int kt = 0; kt < NT; ++kt) {
        if (kt) __syncthreads();           // prior tile's reads complete
        if constexpr (AMODE == 0) {
            gload16(gA, lA);
            gload16(gA + (size_t)64 * K, lA + 2048);
            gA += BK;
        } else {
            *(bf16x8*)(aWr)     = cvt8(A0, A1);
            *(bf16x8*)(aWr + 8) = cvt8(A2, A3);
        }
        if constexpr (BMODE == 0) {
            gload16(gB, lB);
            gload16(gB + (size_t)64 * K, lB + 2048);
            gB += BK;
        } else {
            *(bf16x8*)(bWr)     = cvt8(B0, B1);
            *(bf16x8*)(bWr + 8) = cvt8(B2, B3);
        }
        __syncthreads();                   // drains vmcnt -> tile staged

        if (kt + 1 < NT) {                 // reg prefetch next tile (fp32 paths)
            if constexpr (AMODE == 2) {
                pAf += BK;
                A0 = *(const float4*)(pAf);      A1 = *(const float4*)(pAf + 4);
                A2 = *(const float4*)(pAf + 8);  A3 = *(const float4*)(pAf + 12);
            }
            if constexpr (BMODE == 2) {
                pBf += BK;
                B0 = *(const float4*)(pBf);      B1 = *(const float4*)(pBf + 4);
                B2 = *(const float4*)(pBf + 8);  B3 = *(const float4*)(pBf + 12);
            }
        }

        bf16x8 af[4], bfr[4];
        #pragma unroll
        for (int m = 0; m < 4; ++m) af[m]  = *(const bf16x8*)(aRd + m * 16 * LA);
        #pragma unroll
        for (int n = 0; n < 4; ++n) bfr[n] = *(const bf16x8*)(bRd + n * 16 * LB);
        #pragma unroll
        for (int m = 0; m < 4; ++m)
            #pragma unroll
            for (int n = 0; n < 4; ++n)
                acc[m][n] = __builtin_amdgcn_mfma_f32_16x16x32_bf16(af[m], bfr[n], acc[m][n], 0, 0, 0);
    }

    // Epilogue. C/D layout: col = lane&15, row = (lane>>4)*4 + reg (m89/m91)
    const int orow = tm * BM + wr * 64 + kg * 4;
    const int ocol = tn * BN + wc * 64 + lr;
    if constexpr (OUT_BF16) {
        __bf16* C = (__bf16*)Cp + e * sC;
        #pragma unroll
        for (int m = 0; m < 4; ++m)
            #pragma unroll
            for (int j = 0; j < 4; ++j) {
                const size_t base = (size_t)(orow + m * 16 + j) * N + ocol;
                #pragma unroll
                for (int n = 0; n < 4; ++n) {
                    float v = acc[m][n][j];
                    if (RELU) v = fmaxf(v, 0.f);
                    C[base + n * 16] = (__bf16)v;
                }
            }
    } else {
        float* C = (float*)Cp + e * sC;
        #pragma unroll
        for (int m = 0; m < 4; ++m)
            #pragma unroll
            for (int j = 0; j < 4; ++j) {
                const size_t base = (size_t)(orow + m * 16 + j) * N + ocol;
                #pragma unroll
                for (int n = 0; n < 4; ++n) {
                    float v = acc[m][n][j];
                    if (RELU) v = fmaxf(v, 0.f);
                    C[base + n * 16] = v;
                }
            }
    }
}

extern "C" void kernel_launch(void* const* d_in, const int* in_sizes, int n_in,
                              void* d_out, int out_size, void* d_ws, size_t ws_size,
                              hipStream_t stream) {
    const float* x  = (const float*)d_in[0];   // [8, 2048, 1024]
    const float* w1 = (const float*)d_in[1];   // [8, 4096, 1024]
    const float* w2 = (const float*)d_in[2];   // [8, 1024, 4096]
    float* out = (float*)d_out;                // [8, 2048, 1024]

    const size_t SZ_F  = (size_t)EXPERTS * TOK * DH * sizeof(__bf16);  // 134.2 MB
    const size_t SZ_X  = (size_t)EXPERTS * TOK * DM * sizeof(__bf16);  //  33.6 MB
    const size_t SZ_W1 = (size_t)EXPERTS * DH * DM * sizeof(__bf16);   //  67.1 MB
    const size_t SZ_W2 = (size_t)EXPERTS * DM * DH * sizeof(__bf16);   //  67.1 MB

    char* wsb = (char*)d_ws;
    __bf16* ffn1 = (__bf16*)wsb;

    const dim3 blk(256);
    const dim3 cgrid(2048);
    const int NX  = EXPERTS * TOK * DM / 8;
    const int NW1 = EXPERTS * DH * DM / 8;
    const int NW2 = EXPERTS * DM * DH / 8;

    const size_t eA1 = (size_t)TOK * DM, eB1 = (size_t)DH * DM, eC1 = (size_t)TOK * DH;
    const size_t eA2 = (size_t)TOK * DH, eB2 = (size_t)DM * DH, eC2 = (size_t)TOK * DM;
    const dim3 g1(EXPERTS * (TOK / BM) * (DH / BN));   // 4096
    const dim3 g2(EXPERTS * (TOK / BM) * (DM / BN));   // 1024

    if (ws_size >= SZ_F + SZ_X + SZ_W1 + SZ_W2) {
        // Tier A: everything bf16, both GEMMs full global_load_lds
        __bf16* xb  = (__bf16*)(wsb + SZ_F);
        __bf16* w1b = (__bf16*)(wsb + SZ_F + SZ_X);
        __bf16* w2b = (__bf16*)(wsb + SZ_F + SZ_X + SZ_W1);
        hipLaunchKernelGGL(cvt_bf16, cgrid, blk, 0, stream, x, xb, NX);
        hipLaunchKernelGGL(cvt_bf16, cgrid, blk, 0, stream, w1, w1b, NW1);
        hipLaunchKernelGGL(cvt_bf16, cgrid, blk, 0, stream, w2, w2b, NW2);
        hipLaunchKernelGGL((gemm2<0, 0, true, true>), g1, blk, 0, stream,
            xb, w1b, ffn1, DH, DM, TOK / BM, DH / BN, eA1, eB1, eC1);
        hipLaunchKernelGGL((gemm2<0, 0, false, false>), g2, blk, 0, stream,
            ffn1, w2b, out, DM, DH, TOK / BM, DM / BN, eA2, eB2, eC2);
    } else if (ws_size >= SZ_F + SZ_X + SZ_W1) {
        // Tier B: bf16 x + w1; GEMM2 reads fp32 w2 reg-staged
        __bf16* xb  = (__bf16*)(wsb + SZ_F);
        __bf16* w1b = (__bf16*)(wsb + SZ_F + SZ_X);
        hipLaunchKernelGGL(cvt_bf16, cgrid, blk, 0, stream, x, xb, NX);
        hipLaunchKernelGGL(cvt_bf16, cgrid, blk, 0, stream, w1, w1b, NW1);
        hipLaunchKernelGGL((gemm2<0, 0, true, true>), g1, blk, 0, stream,
            xb, w1b, ffn1, DH, DM, TOK / BM, DH / BN, eA1, eB1, eC1);
        hipLaunchKernelGGL((gemm2<0, 2, false, false>), g2, blk, 0, stream,
            ffn1, w2, out, DM, DH, TOK / BM, DM / BN, eA2, eB2, eC2);
    } else if (ws_size >= SZ_F + SZ_W1) {
        // Tier C: bf16 w1 only
        __bf16* w1b = (__bf16*)(wsb + SZ_F);
        hipLaunchKernelGGL(cvt_bf16, cgrid, blk, 0, stream, w1, w1b, NW1);
        hipLaunchKernelGGL((gemm2<2, 0, true, true>), g1, blk, 0, stream,
            x, w1b, ffn1, DH, DM, TOK / BM, DH / BN, eA1, eB1, eC1);
        hipLaunchKernelGGL((gemm2<0, 2, false, false>), g2, blk, 0, stream,
            ffn1, w2, out, DM, DH, TOK / BM, DM / BN, eA2, eB2, eC2);
    } else if (ws_size >= SZ_F) {
        // Tier D: round-1 style GEMM1; GEMM2 still gets bf16-A gload_lds
        hipLaunchKernelGGL((gemm2<2, 2, true, true>), g1, blk, 0, stream,
            x, w1, ffn1, DH, DM, TOK / BM, DH / BN, eA1, eB1, eC1);
        hipLaunchKernelGGL((gemm2<0, 2, false, false>), g2, blk, 0, stream,
            ffn1, w2, out, DM, DH, TOK / BM, DM / BN, eA2, eB2, eC2);
    } else {
        // Tier E: tiny workspace — chunk token rows per expert
        int rows = (int)((ws_size / ((size_t)DH * sizeof(__bf16))) / BM) * BM;
        if (rows <= 0) rows = BM;
        if (rows > TOK) rows = TOK;
        for (int e = 0; e < EXPERTS; ++e) {
            for (int r0 = 0; r0 < TOK; r0 += rows) {
                int mr = (TOK - r0 < rows) ? (TOK - r0) : rows;
                dim3 cg1((mr / BM) * (DH / BN));
                hipLaunchKernelGGL((gemm2<2, 2, true, true>), cg1, blk, 0, stream,
                    x + ((size_t)e * TOK + r0) * DM, w1 + (size_t)e * DH * DM, ffn1,
                    DH, DM, mr / BM, DH / BN, (size_t)0, (size_t)0, (size_t)0);
                dim3 cg2((mr / BM) * (DM / BN));
                hipLaunchKernelGGL((gemm2<0, 2, false, false>), cg2, blk, 0, stream,
                    ffn1, w2 + (size_t)e * DM * DH, out + ((size_t)e * TOK + r0) * DM,
                    DM, DH, mr / BM, DM / BN, (size_t)0, (size_t)0, (size_t)0);
            }
        }
    }
}

// Round 3
// 382.317 us; speedup vs baseline: 1.5560x; 1.1827x over previous
//
#include <hip/hip_runtime.h>
#include <hip/hip_bf16.h>

#define EXPERTS 8
#define TOK 2048
#define DM 1024
#define DH 4096

#define BM 128
#define BN 128
#define BK 32
#define LSTR 40

typedef __bf16 bf16x8 __attribute__((ext_vector_type(8)));
typedef float  f32x4  __attribute__((ext_vector_type(4)));

static __device__ __forceinline__ bf16x8 cvt8(float4 a, float4 b) {
    bf16x8 r;
    r[0] = (__bf16)a.x; r[1] = (__bf16)a.y; r[2] = (__bf16)a.z; r[3] = (__bf16)a.w;
    r[4] = (__bf16)b.x; r[5] = (__bf16)b.y; r[6] = (__bf16)b.z; r[7] = (__bf16)b.w;
    return r;
}

static __device__ __forceinline__ void gload16(const __bf16* g, __bf16* l) {
    __builtin_amdgcn_global_load_lds(
        (__attribute__((address_space(1))) void*)g,
        (__attribute__((address_space(3))) void*)l, 16, 0, 0);
}

#define BARRIER() asm volatile("s_barrier" ::: "memory")
#define LGKM0()   do { asm volatile("s_waitcnt lgkmcnt(0)" ::: "memory"); \
                       __builtin_amdgcn_sched_barrier(0); } while (0)
#define VMW8()    asm volatile("s_waitcnt vmcnt(8)" ::: "memory")
#define VMW0()    asm volatile("s_waitcnt vmcnt(0)" ::: "memory")

__global__ __launch_bounds__(256)
void cvt_bf16(const float* __restrict__ in, __bf16* __restrict__ out, int n8) {
    int i = blockIdx.x * blockDim.x + threadIdx.x;
    const int stride = gridDim.x * blockDim.x;
    for (; i < n8; i += stride) {
        const float4* p = (const float4*)in + (size_t)i * 2;
        float4 a = p[0], b = p[1];
        *((bf16x8*)out + i) = cvt8(a, b);
    }
}

// ---------------- 256x256 8-phase bf16 GEMM (C = A * B^T) ----------------
// A: M x K row-major bf16, B: N x K row-major bf16.
// 8 waves (2M x 4N), per-wave output 128x64, BK=64, double-buffered 128 KiB LDS.
// Swizzle: LDS[row][cb ^ ((row&7)<<4)] holds G[row][cb]; applied on the
// global source of global_load_lds AND the ds_read address (same involution).
template<bool RELU, bool OUT_BF16>
__global__ __launch_bounds__(512, 2)
void gemm8(const __bf16* __restrict__ Ap, const __bf16* __restrict__ Bp,
           void* __restrict__ Cp, int N, int K, int tiles_m, int tiles_n,
           size_t sA, size_t sB, size_t sC)
{
    __shared__ __bf16 lds[2][2][16384];   // [buf][A/B][256*64] = 128 KiB

    int bid = blockIdx.x;                 // grid % 8 == 0 for all launches
    const int chunk = gridDim.x >> 3;
    bid = (bid & 7) * chunk + (bid >> 3);

    const int per_e = tiles_m * tiles_n;
    const int e  = bid / per_e;
    const int tt = bid - e * per_e;
    const int tn = tt / tiles_m;          // consecutive blocks share B panel
    const int tm = tt - tn * tiles_m;

    const int tid = threadIdx.x;
    const int l   = tid & 63;
    const int wid = tid >> 6;             // 0..7
    const int wr  = wid >> 2;             // 0..1  (M half)
    const int wc  = wid & 3;              // 0..3  (N quarter)
    const int lr  = l & 15;
    const int kg  = l >> 4;               // 0..3
    const int lq  = l >> 3;               // 0..7
    const int swz_e = ((l & 7) ^ lq) << 3;       // staging src col offset, elems

    const int cc0  = (kg * 16) ^ ((l & 7) << 4); // ds_read col byte, kstep 0
    const int cc1  = cc0 ^ 64;                   // kstep 1
    const int rowA = (wr * 128 + lr) * 128;      // byte offset of frag row
    const int rowB = (wc * 64  + lr) * 128;

    const __bf16* Ag = Ap + e * sA + (size_t)(tm * 256) * K;
    const __bf16* Bg = Bp + e * sB + (size_t)(tn * 256) * K;

    // stage half h (128 rows x 64 cols) of matrix mat for K-tile kt2 into buf c2
    auto stage_half = [&](const __bf16* g, int mat, int c2, int h, int kt2) {
        const __bf16* s0 = g + (size_t)(h * 128 + wid * 8 + lq) * K + kt2 * 64 + swz_e;
        gload16(s0,                   &lds[c2][mat][h * 8192 + wid * 512]);
        gload16(s0 + (size_t)64 * K,  &lds[c2][mat][h * 8192 + 4096 + wid * 512]);
    };

    f32x4 acc[8][4];
    #pragma unroll
    for (int m = 0; m < 8; ++m)
        #pragma unroll
        for (int n = 0; n < 4; ++n)
            acc[m][n] = (f32x4){0.f, 0.f, 0.f, 0.f};

    const int NT = K / 64;

    // Prologue: stage tiles 0 and 1 (8 loads each); keep tile 1 in flight.
    stage_half(Ag, 0, 0, 0, 0); stage_half(Ag, 0, 0, 1, 0);
    stage_half(Bg, 1, 0, 0, 0); stage_half(Bg, 1, 0, 1, 0);
    stage_half(Ag, 0, 1, 0, 1); stage_half(Ag, 0, 1, 1, 1);
    stage_half(Bg, 1, 1, 0, 1); stage_half(Bg, 1, 1, 1, 1);
    VMW8();
    BARRIER();

    for (int t = 0; t < NT; ++t) {
        const int c = t & 1;
        const char* Ab = (const char*)&lds[c][0][0] + rowA;
        const char* Bb = (const char*)&lds[c][1][0] + rowB;
        const bool pf = (t + 2 < NT);

        bf16x8 a[4][2], b0[2][2], b1[2][2];

        // ---- P1: read A mf0-3 (8) + B nf0-1 (4); MFMA quad (m-lo x n-lo)
        #pragma unroll
        for (int mf = 0; mf < 4; ++mf) {
            a[mf][0] = *(const bf16x8*)(Ab + mf * 2048 + cc0);
            a[mf][1] = *(const bf16x8*)(Ab + mf * 2048 + cc1);
        }
        #pragma unroll
        for (int nf = 0; nf < 2; ++nf) {
            b0[nf][0] = *(const bf16x8*)(Bb + nf * 2048 + cc0);
            b0[nf][1] = *(const bf16x8*)(Bb + nf * 2048 + cc1);
        }
        BARRIER();
        __builtin_amdgcn_s_setprio(1);
        #pragma unroll
        for (int mf = 0; mf < 4; ++mf)
            #pragma unroll
            for (int nf = 0; nf < 2; ++nf) {
                acc[mf][nf] = __builtin_amdgcn_mfma_f32_16x16x32_bf16(a[mf][0], b0[nf][0], acc[mf][nf], 0, 0, 0);
                acc[mf][nf] = __builtin_amdgcn_mfma_f32_16x16x32_bf16(a[mf][1], b0[nf][1], acc[mf][nf], 0, 0, 0);
            }
        __builtin_amdgcn_s_setprio(0);
        LGKM0();
        BARRIER();

        // ---- P2: read B nf2-3 (4); MFMA (m-lo x n-hi)
        #pragma unroll
        for (int nf = 0; nf < 2; ++nf) {
            b1[nf][0] = *(const bf16x8*)(Bb + (2 + nf) * 2048 + cc0);
            b1[nf][1] = *(const bf16x8*)(Bb + (2 + nf) * 2048 + cc1);
        }
        BARRIER();
        __builtin_amdgcn_s_setprio(1);
        #pragma unroll
        for (int mf = 0; mf < 4; ++mf)
            #pragma unroll
            for (int nf = 0; nf < 2; ++nf) {
                acc[mf][2 + nf] = __builtin_amdgcn_mfma_f32_16x16x32_bf16(a[mf][0], b1[nf][0], acc[mf][2 + nf], 0, 0, 0);
                acc[mf][2 + nf] = __builtin_amdgcn_mfma_f32_16x16x32_bf16(a[mf][1], b1[nf][1], acc[mf][2 + nf], 0, 0, 0);
            }
        __builtin_amdgcn_s_setprio(0);
        LGKM0();
        BARRIER();
        // B region of buf[c] now free block-wide (read in P1+P2 only).

        // ---- P3: read A mf4-7 (8); stage B halves of tile t+2 into buf[c]
        #pragma unroll
        for (int mf = 0; mf < 4; ++mf) {
            a[mf][0] = *(const bf16x8*)(Ab + (4 + mf) * 2048 + cc0);
            a[mf][1] = *(const bf16x8*)(Ab + (4 + mf) * 2048 + cc1);
        }
        if (pf) { stage_half(Bg, 1, c, 0, t + 2); stage_half(Bg, 1, c, 1, t + 2); }
        BARRIER();
        __builtin_amdgcn_s_setprio(1);
        #pragma unroll
        for (int mf = 0; mf < 4; ++mf)
            #pragma unroll
            for (int nf = 0; nf < 2; ++nf) {
                acc[4 + mf][2 + nf] = __builtin_amdgcn_mfma_f32_16x16x32_bf16(a[mf][0], b1[nf][0], acc[4 + mf][2 + nf], 0, 0, 0);
                acc[4 + mf][2 + nf] = __builtin_amdgcn_mfma_f32_16x16x32_bf16(a[mf][1], b1[nf][1], acc[4 + mf][2 + nf], 0, 0, 0);
            }
        __builtin_amdgcn_s_setprio(0);
        LGKM0();
        BARRIER();
        // A region of buf[c] now free block-wide (read in P1+P3).

        // ---- P4: stage A halves of tile t+2; MFMA (m-hi x n-lo)
        if (pf) { stage_half(Ag, 0, c, 0, t + 2); stage_half(Ag, 0, c, 1, t + 2); }
        BARRIER();
        __builtin_amdgcn_s_setprio(1);
        #pragma unroll
        for (int mf = 0; mf < 4; ++mf)
            #pragma unroll
            for (int nf = 0; nf < 2; ++nf) {
                acc[4 + mf][nf] = __builtin_amdgcn_mfma_f32_16x16x32_bf16(a[mf][0], b0[nf][0], acc[4 + mf][nf], 0, 0, 0);
                acc[4 + mf][nf] = __builtin_amdgcn_mfma_f32_16x16x32_bf16(a[mf][1], b0[nf][1], acc[4 + mf][nf], 0, 0, 0);
            }
        __builtin_amdgcn_s_setprio(0);
        LGKM0();
        // Boundary: tile t+1's 8 loads (issued 2 tiles back) must be done.
        // vmcnt(8) retains exactly tile t+2's 8 in-flight loads.
        if (t + 1 < NT) { if (pf) VMW8(); else VMW0(); }
        BARRIER();
    }

    // Epilogue. C/D: col = lane&15, row = (lane>>4)*4 + reg.
    const int orow = tm * 256 + wr * 128 + kg * 4;
    const int ocol = tn * 256 + wc * 64 + lr;
    if constexpr (OUT_BF16) {
        __bf16* C = (__bf16*)Cp + e * sC;
        #pragma unroll
        for (int mf = 0; mf < 8; ++mf)
            #pragma unroll
            for (int j = 0; j < 4; ++j) {
                const size_t base = (size_t)(orow + mf * 16 + j) * N + ocol;
                #pragma unroll
                for (int nf = 0; nf < 4; ++nf) {
                    float v = acc[mf][nf][j];
                    if (RELU) v = fmaxf(v, 0.f);
                    C[base + nf * 16] = (__bf16)v;
                }
            }
    } else {
        float* C = (float*)Cp + e * sC;
        #pragma unroll
        for (int mf = 0; mf < 8; ++mf)
            #pragma unroll
            for (int j = 0; j < 4; ++j) {
                const size_t base = (size_t)(orow + mf * 16 + j) * N + ocol;
                #pragma unroll
                for (int nf = 0; nf < 4; ++nf) {
                    float v = acc[mf][nf][j];
                    if (RELU) v = fmaxf(v, 0.f);
                    C[base + nf * 16] = v;
                }
            }
    }
}

// ---------------- fallback 128x128 kernel (tiers B-E) ----------------
template<int AMODE, int BMODE, bool RELU, bool OUT_BF16>
__global__ __launch_bounds__(256)
void gemm2(const void* __restrict__ Ap, const void* __restrict__ Bp,
           void* __restrict__ Cp, int N, int K, int tiles_m, int tiles_n,
           size_t sA, size_t sB, size_t sC)
{
    constexpr int LA = (AMODE == 0) ? BK : LSTR;
    constexpr int LB = (BMODE == 0) ? BK : LSTR;
    __shared__ __bf16 As[BM * LA];
    __shared__ __bf16 Bs[BN * LB];

    int bid = blockIdx.x;
    const int chunk = gridDim.x >> 3;
    bid = (bid & 7) * chunk + (bid >> 3);

    const int per_e = tiles_m * tiles_n;
    const int e  = bid / per_e;
    const int t  = bid - e * per_e;
    const int tn = t / tiles_m;
    const int tm = t - tn * tiles_m;

    const int tid = threadIdx.x;
    const int l   = tid & 63;
    const int wid = tid >> 6;
    const int wr  = wid >> 1, wc = wid & 1;
    const int lr  = l & 15;
    const int kg  = l >> 4;
    const int srow = tid >> 1;
    const int scol = (tid & 1) << 4;

    const __bf16* gA = nullptr; __bf16* lA = nullptr;
    const float*  pAf = nullptr; __bf16* aWr = nullptr;
    float4 A0, A1, A2, A3;
    if constexpr (AMODE == 0) {
        gA = (const __bf16*)Ap + e * sA
           + (size_t)(tm * BM + wid * 16 + (l >> 2)) * K + (l & 3) * 8;
        lA = As + wid * 512;
    } else {
        pAf = (const float*)Ap + e * sA + (size_t)(tm * BM + srow) * K + scol;
        aWr = As + srow * LA + scol;
        A0 = *(const float4*)(pAf);      A1 = *(const float4*)(pAf + 4);
        A2 = *(const float4*)(pAf + 8);  A3 = *(const float4*)(pAf + 12);
    }
    const __bf16* gB = nullptr; __bf16* lB = nullptr;
    const float*  pBf = nullptr; __bf16* bWr = nullptr;
    float4 B0, B1, B2, B3;
    if constexpr (BMODE == 0) {
        gB = (const __bf16*)Bp + e * sB
           + (size_t)(tn * BN + wid * 16 + (l >> 2)) * K + (l & 3) * 8;
        lB = Bs + wid * 512;
    } else {
        pBf = (const float*)Bp + e * sB + (size_t)(tn * BN + srow) * K + scol;
        bWr = Bs + srow * LB + scol;
        B0 = *(const float4*)(pBf);      B1 = *(const float4*)(pBf + 4);
        B2 = *(const float4*)(pBf + 8);  B3 = *(const float4*)(pBf + 12);
    }

    const __bf16* aRd = As + (wr * 64 + lr) * LA + kg * 8;
    const __bf16* bRd = Bs + (wc * 64 + lr) * LB + kg * 8;

    f32x4 acc[4][4];
    #pragma unroll
    for (int m = 0; m < 4; ++m)
        #pragma unroll
        for (int n = 0; n < 4; ++n)
            acc[m][n] = (f32x4){0.f, 0.f, 0.f, 0.f};

    const int NT = K / BK;
    for (int kt = 0; kt < NT; ++kt) {
        if (kt) __syncthreads();
        if constexpr (AMODE == 0) {
            gload16(gA, lA);
            gload16(gA + (size_t)64 * K, lA + 2048);
            gA += BK;
        } else {
            *(bf16x8*)(aWr)     = cvt8(A0, A1);
            *(bf16x8*)(aWr + 8) = cvt8(A2, A3);
        }
        if constexpr (BMODE == 0) {
            gload16(gB, lB);
            gload16(gB + (size_t)64 * K, lB + 2048);
            gB += BK;
        } else {
            *(bf16x8*)(bWr)     = cvt8(B0, B1);
            *(bf16x8*)(bWr + 8) = cvt8(B2, B3);
        }
        __syncthreads();

        if (kt + 1 < NT) {
            if constexpr (AMODE == 2) {
                pAf += BK;
                A0 = *(const float4*)(pAf);      A1 = *(const float4*)(pAf + 4);
                A2 = *(const float4*)(pAf + 8);  A3 = *(const float4*)(pAf + 12);
            }
            if constexpr (BMODE == 2) {
                pBf += BK;
                B0 = *(const float4*)(pBf);      B1 = *(const float4*)(pBf + 4);
                B2 = *(const float4*)(pBf + 8);  B3 = *(const float4*)(pBf + 12);
            }
        }

        bf16x8 af[4], bfr[4];
        #pragma unroll
        for (int m = 0; m < 4; ++m) af[m]  = *(const bf16x8*)(aRd + m * 16 * LA);
        #pragma unroll
        for (int n = 0; n < 4; ++n) bfr[n] = *(const bf16x8*)(bRd + n * 16 * LB);
        #pragma unroll
        for (int m = 0; m < 4; ++m)
            #pragma unroll
            for (int n = 0; n < 4; ++n)
                acc[m][n] = __builtin_amdgcn_mfma_f32_16x16x32_bf16(af[m], bfr[n], acc[m][n], 0, 0, 0);
    }

    const int orow = tm * BM + wr * 64 + kg * 4;
    const int ocol = tn * BN + wc * 64 + lr;
    if constexpr (OUT_BF16) {
        __bf16* C = (__bf16*)Cp + e * sC;
        #pragma unroll
        for (int m = 0; m < 4; ++m)
            #pragma unroll
            for (int j = 0; j < 4; ++j) {
                const size_t base = (size_t)(orow + m * 16 + j) * N + ocol;
                #pragma unroll
                for (int n = 0; n < 4; ++n) {
                    float v = acc[m][n][j];
                    if (RELU) v = fmaxf(v, 0.f);
                    C[base + n * 16] = (__bf16)v;
                }
            }
    } else {
        float* C = (float*)Cp + e * sC;
        #pragma unroll
        for (int m = 0; m < 4; ++m)
            #pragma unroll
            for (int j = 0; j < 4; ++j) {
                const size_t base = (size_t)(orow + m * 16 + j) * N + ocol;
                #pragma unroll
                for (int n = 0; n < 4; ++n) {
                    float v = acc[m][n][j];
                    if (RELU) v = fmaxf(v, 0.f);
                    C[base + n * 16] = v;
                }
            }
    }
}

extern "C" void kernel_launch(void* const* d_in, const int* in_sizes, int n_in,
                              void* d_out, int out_size, void* d_ws, size_t ws_size,
                              hipStream_t stream) {
    const float* x  = (const float*)d_in[0];   // [8, 2048, 1024]
    const float* w1 = (const float*)d_in[1];   // [8, 4096, 1024]
    const float* w2 = (const float*)d_in[2];   // [8, 1024, 4096]
    float* out = (float*)d_out;                // [8, 2048, 1024]

    const size_t SZ_F  = (size_t)EXPERTS * TOK * DH * sizeof(__bf16);  // 134.2 MB
    const size_t SZ_X  = (size_t)EXPERTS * TOK * DM * sizeof(__bf16);
    const size_t SZ_W1 = (size_t)EXPERTS * DH * DM * sizeof(__bf16);
    const size_t SZ_W2 = (size_t)EXPERTS * DM * DH * sizeof(__bf16);

    char* wsb = (char*)d_ws;
    __bf16* ffn1 = (__bf16*)wsb;

    const dim3 blk(256);
    const dim3 cgrid(2048);
    const int NX  = EXPERTS * TOK * DM / 8;
    const int NW1 = EXPERTS * DH * DM / 8;
    const int NW2 = EXPERTS * DM * DH / 8;

    const size_t eA1 = (size_t)TOK * DM, eB1 = (size_t)DH * DM, eC1 = (size_t)TOK * DH;
    const size_t eA2 = (size_t)TOK * DH, eB2 = (size_t)DM * DH, eC2 = (size_t)TOK * DM;

    if (ws_size >= SZ_F + SZ_X + SZ_W1 + SZ_W2) {
        // Tier A: everything bf16; both GEMMs on the 256x256 8-phase kernel
        __bf16* xb  = (__bf16*)(wsb + SZ_F);
        __bf16* w1b = (__bf16*)(wsb + SZ_F + SZ_X);
        __bf16* w2b = (__bf16*)(wsb + SZ_F + SZ_X + SZ_W1);
        hipLaunchKernelGGL(cvt_bf16, cgrid, blk, 0, stream, x, xb, NX);
        hipLaunchKernelGGL(cvt_bf16, cgrid, blk, 0, stream, w1, w1b, NW1);
        hipLaunchKernelGGL(cvt_bf16, cgrid, blk, 0, stream, w2, w2b, NW2);
        const dim3 g1(EXPERTS * (TOK / 256) * (DH / 256));   // 8*8*16 = 1024
        const dim3 g2(EXPERTS * (TOK / 256) * (DM / 256));   // 8*8*4  = 256
        hipLaunchKernelGGL((gemm8<true, true>), g1, dim3(512), 0, stream,
            xb, w1b, ffn1, DH, DM, TOK / 256, DH / 256, eA1, eB1, eC1);
        hipLaunchKernelGGL((gemm8<false, false>), g2, dim3(512), 0, stream,
            ffn1, w2b, out, DM, DH, TOK / 256, DM / 256, eA2, eB2, eC2);
    } else if (ws_size >= SZ_F + SZ_X + SZ_W1) {
        __bf16* xb  = (__bf16*)(wsb + SZ_F);
        __bf16* w1b = (__bf16*)(wsb + SZ_F + SZ_X);
        hipLaunchKernelGGL(cvt_bf16, cgrid, blk, 0, stream, x, xb, NX);
        hipLaunchKernelGGL(cvt_bf16, cgrid, blk, 0, stream, w1, w1b, NW1);
        const dim3 g1(EXPERTS * (TOK / BM) * (DH / BN));
        const dim3 g2(EXPERTS * (TOK / BM) * (DM / BN));
        hipLaunchKernelGGL((gemm2<0, 0, true, true>), g1, blk, 0, stream,
            xb, w1b, ffn1, DH, DM, TOK / BM, DH / BN, eA1, eB1, eC1);
        hipLaunchKernelGGL((gemm2<0, 2, false, false>), g2, blk, 0, stream,
            ffn1, w2, out, DM, DH, TOK / BM, DM / BN, eA2, eB2, eC2);
    } else if (ws_size >= SZ_F + SZ_W1) {
        __bf16* w1b = (__bf16*)(wsb + SZ_F);
        hipLaunchKernelGGL(cvt_bf16, cgrid, blk, 0, stream, w1, w1b, NW1);
        const dim3 g1(EXPERTS * (TOK / BM) * (DH / BN));
        const dim3 g2(EXPERTS * (TOK / BM) * (DM / BN));
        hipLaunchKernelGGL((gemm2<2, 0, true, true>), g1, blk, 0, stream,
            x, w1b, ffn1, DH, DM, TOK / BM, DH / BN, eA1, eB1, eC1);
        hipLaunchKernelGGL((gemm2<0, 2, false, false>), g2, blk, 0, stream,
            ffn1, w2, out, DM, DH, TOK / BM, DM / BN, eA2, eB2, eC2);
    } else if (ws_size >= SZ_F) {
        const dim3 g1(EXPERTS * (TOK / BM) * (DH / BN));
        const dim3 g2(EXPERTS * (TOK / BM) * (DM / BN));
        hipLaunchKernelGGL((gemm2<2, 2, true, true>), g1, blk, 0, stream,
            x, w1, ffn1, DH, DM, TOK / BM, DH / BN, eA1, eB1, eC1);
        hipLaunchKernelGGL((gemm2<0, 2, false, false>), g2, blk, 0, stream,
            ffn1, w2, out, DM, DH, TOK / BM, DM / BN, eA2, eB2, eC2);
    } else {
        int rows = (int)((ws_size / ((size_t)DH * sizeof(__bf16))) / BM) * BM;
        if (rows <= 0) rows = BM;
        if (rows > TOK) rows = TOK;
        for (int e = 0; e < EXPERTS; ++e) {
            for (int r0 = 0; r0 < TOK; r0 += rows) {
                int mr = (TOK - r0 < rows) ? (TOK - r0) : rows;
                dim3 cg1((mr / BM) * (DH / BN));
                hipLaunchKernelGGL((gemm2<2, 2, true, true>), cg1, blk, 0, stream,
                    x + ((size_t)e * TOK + r0) * DM, w1 + (size_t)e * DH * DM, ffn1,
                    DH, DM, mr / BM, DH / BN, (size_t)0, (size_t)0, (size_t)0);
                dim3 cg2((mr / BM) * (DM / BN));
                hipLaunchKernelGGL((gemm2<0, 2, false, false>), cg2, blk, 0, stream,
                    ffn1, w2 + (size_t)e * DM * DH, out + ((size_t)e * TOK + r0) * DM,
                    DM, DH, mr / BM, DM / BN, (size_t)0, (size_t)0, (size_t)0);
            }
        }
    }
}

// Round 4
// 364.496 us; speedup vs baseline: 1.6321x; 1.0489x over previous
//
#include <hip/hip_runtime.h>
#include <hip/hip_bf16.h>

#define EXPERTS 8
#define TOK 2048
#define DM 1024
#define DH 4096

#define BM 128
#define BN 128
#define BK 32
#define LSTR 40

typedef __bf16 bf16x8 __attribute__((ext_vector_type(8)));
typedef float  f32x4  __attribute__((ext_vector_type(4)));

static __device__ __forceinline__ bf16x8 cvt8(float4 a, float4 b) {
    bf16x8 r;
    r[0] = (__bf16)a.x; r[1] = (__bf16)a.y; r[2] = (__bf16)a.z; r[3] = (__bf16)a.w;
    r[4] = (__bf16)b.x; r[5] = (__bf16)b.y; r[6] = (__bf16)b.z; r[7] = (__bf16)b.w;
    return r;
}

static __device__ __forceinline__ void gload16(const __bf16* g, __bf16* l) {
    __builtin_amdgcn_global_load_lds(
        (__attribute__((address_space(1))) void*)g,
        (__attribute__((address_space(3))) void*)l, 16, 0, 0);
}

#define BARRIER() asm volatile("s_barrier" ::: "memory")
#define LGKMC(n)  do { asm volatile("s_waitcnt lgkmcnt(" #n ")" ::: "memory"); \
                       __builtin_amdgcn_sched_barrier(0); } while (0)
#define VMW8()    asm volatile("s_waitcnt vmcnt(8)" ::: "memory")
#define VMW0()    asm volatile("s_waitcnt vmcnt(0)" ::: "memory")

// single fused fp32->bf16 convert for x, w1, w2 (one launch)
__global__ __launch_bounds__(256)
void cvt_all(const float* __restrict__ x,  const float* __restrict__ w1,
             const float* __restrict__ w2, __bf16* __restrict__ xb,
             __bf16* __restrict__ w1b,     __bf16* __restrict__ w2b,
             int nx, int nw1, int ntot) {
    int i = blockIdx.x * blockDim.x + threadIdx.x;
    const int stride = gridDim.x * blockDim.x;
    for (; i < ntot; i += stride) {
        const float* src; __bf16* dst; int off;
        if (i < nx)            { src = x;  dst = xb;  off = i; }
        else if (i < nx + nw1) { src = w1; dst = w1b; off = i - nx; }
        else                   { src = w2; dst = w2b; off = i - nx - nw1; }
        const float4* p = (const float4*)src + (size_t)off * 2;
        float4 a = p[0], b = p[1];
        *((bf16x8*)dst + off) = cvt8(a, b);
    }
}

// ---------------- 256x256 pipelined 4-barrier bf16 GEMM (C = A * B^T) -------
// 8 waves (2Mx4N), per-wave 128x64 out, BK=64, 128 KiB dbuf LDS, swizzled.
// Schedule per K-tile (1 barrier/phase; ds_reads issued one phase early,
// counted lgkmcnt waits; stages issued after the barrier that follows the
// completion of ALL reads of the staged region):
//  P1: issue B2-3(t);             lgkm(4)  [A0-3,B0-1 done]; bar; MFMA Q1(a,b0)
//  P2: issue A4-7(t);             lgkm(8)  [B2-3 done];      bar; stage B(t+2); MFMA Q2(a,b1)
//  P3:                            lgkm(0)  [A4-7 done];      bar; stage A(t+2); MFMA Q3(a2,b1)
//  P4: vmcnt(8) [t+1 landed]; bar; issue A0-3(t+1); MFMA Q4(a2,b0); issue B0-1(t+1)
template<bool RELU, bool OUT_BF16>
__global__ __launch_bounds__(512, 2)
void gemm8(const __bf16* __restrict__ Ap, const __bf16* __restrict__ Bp,
           void* __restrict__ Cp, int N, int K, int tiles_m, int tiles_n,
           size_t sA, size_t sB, size_t sC)
{
    __shared__ __bf16 lds[2][2][16384];   // [buf][A/B][256*64] = 128 KiB

    int bid = blockIdx.x;                 // grid % 8 == 0 for all launches
    const int chunk = gridDim.x >> 3;
    bid = (bid & 7) * chunk + (bid >> 3);

    const int per_e = tiles_m * tiles_n;
    const int e  = bid / per_e;
    const int tt = bid - e * per_e;
    const int tn = tt / tiles_m;          // consecutive blocks share B panel
    const int tm = tt - tn * tiles_m;

    const int tid = threadIdx.x;
    const int l   = tid & 63;
    const int wid = tid >> 6;             // 0..7
    const int wr  = wid >> 2;             // 0..1
    const int wc  = wid & 3;              // 0..3
    const int lr  = l & 15;
    const int kg  = l >> 4;               // 0..3
    const int lq  = l >> 3;               // 0..7
    const int swz_e = ((l & 7) ^ lq) << 3;        // staging src col offset (elems)

    const int cc0  = (kg * 16) ^ ((l & 7) << 4);  // ds_read col byte, kstep 0
    const int cc1  = cc0 ^ 64;                    // kstep 1
    const int rowA = (wr * 128 + lr) * 128;
    const int rowB = (wc * 64  + lr) * 128;

    const __bf16* Ag = Ap + e * sA + (size_t)(tm * 256) * K;
    const __bf16* Bg = Bp + e * sB + (size_t)(tn * 256) * K;

    auto stage_half = [&](const __bf16* g, int mat, int c2, int h, int kt2) {
        const __bf16* s0 = g + (size_t)(h * 128 + wid * 8 + lq) * K + kt2 * 64 + swz_e;
        gload16(s0,                  &lds[c2][mat][h * 8192 + wid * 512]);
        gload16(s0 + (size_t)64 * K, &lds[c2][mat][h * 8192 + 4096 + wid * 512]);
    };

    f32x4 acc[8][4];
    #pragma unroll
    for (int m = 0; m < 8; ++m)
        #pragma unroll
        for (int n = 0; n < 4; ++n)
            acc[m][n] = (f32x4){0.f, 0.f, 0.f, 0.f};

    const int NT = K / 64;                // >= 2 for all our launches

    // Prologue: stage tiles 0,1; wait tile 0; pre-issue A0-3,B0-1 of tile 0.
    stage_half(Ag, 0, 0, 0, 0); stage_half(Ag, 0, 0, 1, 0);
    stage_half(Bg, 1, 0, 0, 0); stage_half(Bg, 1, 0, 1, 0);
    stage_half(Ag, 0, 1, 0, 1); stage_half(Ag, 0, 1, 1, 1);
    stage_half(Bg, 1, 1, 0, 1); stage_half(Bg, 1, 1, 1, 1);
    VMW8();
    BARRIER();

    bf16x8 a[4][2], a2[4][2], b0[2][2], b1[2][2];
    {
        const char* Ab = (const char*)&lds[0][0][0] + rowA;
        const char* Bb = (const char*)&lds[0][1][0] + rowB;
        #pragma unroll
        for (int mf = 0; mf < 4; ++mf) {
            a[mf][0] = *(const bf16x8*)(Ab + mf * 2048 + cc0);
            a[mf][1] = *(const bf16x8*)(Ab + mf * 2048 + cc1);
        }
        #pragma unroll
        for (int nf = 0; nf < 2; ++nf) {
            b0[nf][0] = *(const bf16x8*)(Bb + nf * 2048 + cc0);
            b0[nf][1] = *(const bf16x8*)(Bb + nf * 2048 + cc1);
        }
    }

    for (int t = 0; t < NT; ++t) {
        const int c = t & 1;
        const char* Ab  = (const char*)&lds[c][0][0] + rowA;
        const char* Bb  = (const char*)&lds[c][1][0] + rowB;
        const char* Abn = (const char*)&lds[c ^ 1][0][0] + rowA;
        const char* Bbn = (const char*)&lds[c ^ 1][1][0] + rowB;
        const bool pf   = (t + 2 < NT);
        const bool more = (t + 1 < NT);

        // ---- P1
        #pragma unroll
        for (int nf = 0; nf < 2; ++nf) {
            b1[nf][0] = *(const bf16x8*)(Bb + (2 + nf) * 2048 + cc0);
            b1[nf][1] = *(const bf16x8*)(Bb + (2 + nf) * 2048 + cc1);
        }
        LGKMC(4);                  // a, b0 complete; b1 (4) outstanding
        BARRIER();
        __builtin_amdgcn_s_setprio(1);
        #pragma unroll
        for (int mf = 0; mf < 4; ++mf)
            #pragma unroll
            for (int nf = 0; nf < 2; ++nf) {
                acc[mf][nf] = __builtin_amdgcn_mfma_f32_16x16x32_bf16(a[mf][0], b0[nf][0], acc[mf][nf], 0, 0, 0);
                acc[mf][nf] = __builtin_amdgcn_mfma_f32_16x16x32_bf16(a[mf][1], b0[nf][1], acc[mf][nf], 0, 0, 0);
            }
        __builtin_amdgcn_s_setprio(0);

        // ---- P2
        #pragma unroll
        for (int mf = 0; mf < 4; ++mf) {
            a2[mf][0] = *(const bf16x8*)(Ab + (4 + mf) * 2048 + cc0);
            a2[mf][1] = *(const bf16x8*)(Ab + (4 + mf) * 2048 + cc1);
        }
        LGKMC(8);                  // b1 complete; a2 (8) outstanding
        BARRIER();                 // all waves' B-reads of buf[c] done -> B free
        if (pf) { stage_half(Bg, 1, c, 0, t + 2); stage_half(Bg, 1, c, 1, t + 2); }
        __builtin_amdgcn_s_setprio(1);
        #pragma unroll
        for (int mf = 0; mf < 4; ++mf)
            #pragma unroll
            for (int nf = 0; nf < 2; ++nf) {
                acc[mf][2 + nf] = __builtin_amdgcn_mfma_f32_16x16x32_bf16(a[mf][0], b1[nf][0], acc[mf][2 + nf], 0, 0, 0);
                acc[mf][2 + nf] = __builtin_amdgcn_mfma_f32_16x16x32_bf16(a[mf][1], b1[nf][1], acc[mf][2 + nf], 0, 0, 0);
            }
        __builtin_amdgcn_s_setprio(0);

        // ---- P3
        LGKMC(0);                  // a2 complete
        BARRIER();                 // all waves' A-reads of buf[c] done -> A free
        if (pf) { stage_half(Ag, 0, c, 0, t + 2); stage_half(Ag, 0, c, 1, t + 2); }
        __builtin_amdgcn_s_setprio(1);
        #pragma unroll
        for (int mf = 0; mf < 4; ++mf)
            #pragma unroll
            for (int nf = 0; nf < 2; ++nf) {
                acc[4 + mf][2 + nf] = __builtin_amdgcn_mfma_f32_16x16x32_bf16(a2[mf][0], b1[nf][0], acc[4 + mf][2 + nf], 0, 0, 0);
                acc[4 + mf][2 + nf] = __builtin_amdgcn_mfma_f32_16x16x32_bf16(a2[mf][1], b1[nf][1], acc[4 + mf][2 + nf], 0, 0, 0);
            }
        __builtin_amdgcn_s_setprio(0);

        // ---- P4
        if (more) { if (pf) VMW8(); else VMW0(); }   // tile t+1 fully landed
        BARRIER();
        if (more) {
            #pragma unroll
            for (int mf = 0; mf < 4; ++mf) {
                a[mf][0] = *(const bf16x8*)(Abn + mf * 2048 + cc0);
                a[mf][1] = *(const bf16x8*)(Abn + mf * 2048 + cc1);
            }
        }
        __builtin_amdgcn_s_setprio(1);
        #pragma unroll
        for (int mf = 0; mf < 4; ++mf)
            #pragma unroll
            for (int nf = 0; nf < 2; ++nf) {
                acc[4 + mf][nf] = __builtin_amdgcn_mfma_f32_16x16x32_bf16(a2[mf][0], b0[nf][0], acc[4 + mf][nf], 0, 0, 0);
                acc[4 + mf][nf] = __builtin_amdgcn_mfma_f32_16x16x32_bf16(a2[mf][1], b0[nf][1], acc[4 + mf][nf], 0, 0, 0);
            }
        __builtin_amdgcn_s_setprio(0);
        if (more) {
            #pragma unroll
            for (int nf = 0; nf < 2; ++nf) {
                b0[nf][0] = *(const bf16x8*)(Bbn + nf * 2048 + cc0);
                b0[nf][1] = *(const bf16x8*)(Bbn + nf * 2048 + cc1);
            }
        }
    }

    // Epilogue. C/D: col = lane&15, row = (lane>>4)*4 + reg.
    const int orow = tm * 256 + wr * 128 + kg * 4;
    const int ocol = tn * 256 + wc * 64 + lr;
    if constexpr (OUT_BF16) {
        __bf16* C = (__bf16*)Cp + e * sC;
        #pragma unroll
        for (int mf = 0; mf < 8; ++mf)
            #pragma unroll
            for (int j = 0; j < 4; ++j) {
                const size_t base = (size_t)(orow + mf * 16 + j) * N + ocol;
                #pragma unroll
                for (int nf = 0; nf < 4; ++nf) {
                    float v = acc[mf][nf][j];
                    if (RELU) v = fmaxf(v, 0.f);
                    C[base + nf * 16] = (__bf16)v;
                }
            }
    } else {
        float* C = (float*)Cp + e * sC;
        #pragma unroll
        for (int mf = 0; mf < 8; ++mf)
            #pragma unroll
            for (int j = 0; j < 4; ++j) {
                const size_t base = (size_t)(orow + mf * 16 + j) * N + ocol;
                #pragma unroll
                for (int nf = 0; nf < 4; ++nf) {
                    float v = acc[mf][nf][j];
                    if (RELU) v = fmaxf(v, 0.f);
                    C[base + nf * 16] = v;
                }
            }
    }
}

// ---------------- fallback 128x128 kernel (tiers B-E) ----------------
template<int AMODE, int BMODE, bool RELU, bool OUT_BF16>
__global__ __launch_bounds__(256)
void gemm2(const void* __restrict__ Ap, const void* __restrict__ Bp,
           void* __restrict__ Cp, int N, int K, int tiles_m, int tiles_n,
           size_t sA, size_t sB, size_t sC)
{
    constexpr int LA = (AMODE == 0) ? BK : LSTR;
    constexpr int LB = (BMODE == 0) ? BK : LSTR;
    __shared__ __bf16 As[BM * LA];
    __shared__ __bf16 Bs[BN * LB];

    int bid = blockIdx.x;
    const int chunk = gridDim.x >> 3;
    bid = (bid & 7) * chunk + (bid >> 3);

    const int per_e = tiles_m * tiles_n;
    const int e  = bid / per_e;
    const int t  = bid - e * per_e;
    const int tn = t / tiles_m;
    const int tm = t - tn * tiles_m;

    const int tid = threadIdx.x;
    const int l   = tid & 63;
    const int wid = tid >> 6;
    const int wr  = wid >> 1, wc = wid & 1;
    const int lr  = l & 15;
    const int kg  = l >> 4;
    const int srow = tid >> 1;
    const int scol = (tid & 1) << 4;

    const __bf16* gA = nullptr; __bf16* lA = nullptr;
    const float*  pAf = nullptr; __bf16* aWr = nullptr;
    float4 A0, A1, A2, A3;
    if constexpr (AMODE == 0) {
        gA = (const __bf16*)Ap + e * sA
           + (size_t)(tm * BM + wid * 16 + (l >> 2)) * K + (l & 3) * 8;
        lA = As + wid * 512;
    } else {
        pAf = (const float*)Ap + e * sA + (size_t)(tm * BM + srow) * K + scol;
        aWr = As + srow * LA + scol;
        A0 = *(const float4*)(pAf);      A1 = *(const float4*)(pAf + 4);
        A2 = *(const float4*)(pAf + 8);  A3 = *(const float4*)(pAf + 12);
    }
    const __bf16* gB = nullptr; __bf16* lB = nullptr;
    const float*  pBf = nullptr; __bf16* bWr = nullptr;
    float4 B0, B1, B2, B3;
    if constexpr (BMODE == 0) {
        gB = (const __bf16*)Bp + e * sB
           + (size_t)(tn * BN + wid * 16 + (l >> 2)) * K + (l & 3) * 8;
        lB = Bs + wid * 512;
    } else {
        pBf = (const float*)Bp + e * sB + (size_t)(tn * BN + srow) * K + scol;
        bWr = Bs + srow * LB + scol;
        B0 = *(const float4*)(pBf);      B1 = *(const float4*)(pBf + 4);
        B2 = *(const float4*)(pBf + 8);  B3 = *(const float4*)(pBf + 12);
    }

    const __bf16* aRd = As + (wr * 64 + lr) * LA + kg * 8;
    const __bf16* bRd = Bs + (wc * 64 + lr) * LB + kg * 8;

    f32x4 acc[4][4];
    #pragma unroll
    for (int m = 0; m < 4; ++m)
        #pragma unroll
        for (int n = 0; n < 4; ++n)
            acc[m][n] = (f32x4){0.f, 0.f, 0.f, 0.f};

    const int NT = K / BK;
    for (int kt = 0; kt < NT; ++kt) {
        if (kt) __syncthreads();
        if constexpr (AMODE == 0) {
            gload16(gA, lA);
            gload16(gA + (size_t)64 * K, lA + 2048);
            gA += BK;
        } else {
            *(bf16x8*)(aWr)     = cvt8(A0, A1);
            *(bf16x8*)(aWr + 8) = cvt8(A2, A3);
        }
        if constexpr (BMODE == 0) {
            gload16(gB, lB);
            gload16(gB + (size_t)64 * K, lB + 2048);
            gB += BK;
        } else {
            *(bf16x8*)(bWr)     = cvt8(B0, B1);
            *(bf16x8*)(bWr + 8) = cvt8(B2, B3);
        }
        __syncthreads();

        if (kt + 1 < NT) {
            if constexpr (AMODE == 2) {
                pAf += BK;
                A0 = *(const float4*)(pAf);      A1 = *(const float4*)(pAf + 4);
                A2 = *(const float4*)(pAf + 8);  A3 = *(const float4*)(pAf + 12);
            }
            if constexpr (BMODE == 2) {
                pBf += BK;
                B0 = *(const float4*)(pBf);      B1 = *(const float4*)(pBf + 4);
                B2 = *(const float4*)(pBf + 8);  B3 = *(const float4*)(pBf + 12);
            }
        }

        bf16x8 af[4], bfr[4];
        #pragma unroll
        for (int m = 0; m < 4; ++m) af[m]  = *(const bf16x8*)(aRd + m * 16 * LA);
        #pragma unroll
        for (int n = 0; n < 4; ++n) bfr[n] = *(const bf16x8*)(bRd + n * 16 * LB);
        #pragma unroll
        for (int m = 0; m < 4; ++m)
            #pragma unroll
            for (int n = 0; n < 4; ++n)
                acc[m][n] = __builtin_amdgcn_mfma_f32_16x16x32_bf16(af[m], bfr[n], acc[m][n], 0, 0, 0);
    }

    const int orow = tm * BM + wr * 64 + kg * 4;
    const int ocol = tn * BN + wc * 64 + lr;
    if constexpr (OUT_BF16) {
        __bf16* C = (__bf16*)Cp + e * sC;
        #pragma unroll
        for (int m = 0; m < 4; ++m)
            #pragma unroll
            for (int j = 0; j < 4; ++j) {
                const size_t base = (size_t)(orow + m * 16 + j) * N + ocol;
                #pragma unroll
                for (int n = 0; n < 4; ++n) {
                    float v = acc[m][n][j];
                    if (RELU) v = fmaxf(v, 0.f);
                    C[base + n * 16] = (__bf16)v;
                }
            }
    } else {
        float* C = (float*)Cp + e * sC;
        #pragma unroll
        for (int m = 0; m < 4; ++m)
            #pragma unroll
            for (int j = 0; j < 4; ++j) {
                const size_t base = (size_t)(orow + m * 16 + j) * N + ocol;
                #pragma unroll
                for (int n = 0; n < 4; ++n) {
                    float v = acc[m][n][j];
                    if (RELU) v = fmaxf(v, 0.f);
                    C[base + n * 16] = v;
                }
            }
    }
}

extern "C" void kernel_launch(void* const* d_in, const int* in_sizes, int n_in,
                              void* d_out, int out_size, void* d_ws, size_t ws_size,
                              hipStream_t stream) {
    const float* x  = (const float*)d_in[0];   // [8, 2048, 1024]
    const float* w1 = (const float*)d_in[1];   // [8, 4096, 1024]
    const float* w2 = (const float*)d_in[2];   // [8, 1024, 4096]
    float* out = (float*)d_out;                // [8, 2048, 1024]

    const size_t SZ_F  = (size_t)EXPERTS * TOK * DH * sizeof(__bf16);  // 134.2 MB
    const size_t SZ_X  = (size_t)EXPERTS * TOK * DM * sizeof(__bf16);
    const size_t SZ_W1 = (size_t)EXPERTS * DH * DM * sizeof(__bf16);
    const size_t SZ_W2 = (size_t)EXPERTS * DM * DH * sizeof(__bf16);

    char* wsb = (char*)d_ws;
    __bf16* ffn1 = (__bf16*)wsb;

    const dim3 blk(256);
    const dim3 cgrid(2048);
    const int NX  = EXPERTS * TOK * DM / 8;
    const int NW1 = EXPERTS * DH * DM / 8;
    const int NW2 = EXPERTS * DM * DH / 8;

    const size_t eA1 = (size_t)TOK * DM, eB1 = (size_t)DH * DM, eC1 = (size_t)TOK * DH;
    const size_t eA2 = (size_t)TOK * DH, eB2 = (size_t)DM * DH, eC2 = (size_t)TOK * DM;

    if (ws_size >= SZ_F + SZ_X + SZ_W1 + SZ_W2) {
        // Tier A: fused cvt, then both GEMMs on the pipelined 256x256 kernel
        __bf16* xb  = (__bf16*)(wsb + SZ_F);
        __bf16* w1b = (__bf16*)(wsb + SZ_F + SZ_X);
        __bf16* w2b = (__bf16*)(wsb + SZ_F + SZ_X + SZ_W1);
        hipLaunchKernelGGL(cvt_all, cgrid, blk, 0, stream,
            x, w1, w2, xb, w1b, w2b, NX, NW1, NX + NW1 + NW2);
        const dim3 g1(EXPERTS * (TOK / 256) * (DH / 256));   // 1024
        const dim3 g2(EXPERTS * (TOK / 256) * (DM / 256));   // 256
        hipLaunchKernelGGL((gemm8<true, true>), g1, dim3(512), 0, stream,
            xb, w1b, ffn1, DH, DM, TOK / 256, DH / 256, eA1, eB1, eC1);
        hipLaunchKernelGGL((gemm8<false, false>), g2, dim3(512), 0, stream,
            ffn1, w2b, out, DM, DH, TOK / 256, DM / 256, eA2, eB2, eC2);
    } else if (ws_size >= SZ_F + SZ_X + SZ_W1) {
        __bf16* xb  = (__bf16*)(wsb + SZ_F);
        __bf16* w1b = (__bf16*)(wsb + SZ_F + SZ_X);
        hipLaunchKernelGGL(cvt_all, cgrid, blk, 0, stream,
            x, w1, w1, xb, w1b, w1b, NX, NW1, NX + NW1);
        const dim3 g1(EXPERTS * (TOK / 256) * (DH / 256));
        const dim3 g2(EXPERTS * (TOK / BM) * (DM / BN));
        hipLaunchKernelGGL((gemm8<true, true>), g1, dim3(512), 0, stream,
            xb, w1b, ffn1, DH, DM, TOK / 256, DH / 256, eA1, eB1, eC1);
        hipLaunchKernelGGL((gemm2<0, 2, false, false>), g2, blk, 0, stream,
            ffn1, w2, out, DM, DH, TOK / BM, DM / BN, eA2, eB2, eC2);
    } else if (ws_size >= SZ_F + SZ_W1) {
        __bf16* w1b = (__bf16*)(wsb + SZ_F);
        hipLaunchKernelGGL(cvt_all, cgrid, blk, 0, stream,
            w1, w1, w1, w1b, w1b, w1b, NW1, 0, NW1);
        const dim3 g1(EXPERTS * (TOK / BM) * (DH / BN));
        const dim3 g2(EXPERTS * (TOK / BM) * (DM / BN));
        hipLaunchKernelGGL((gemm2<2, 0, true, true>), g1, blk, 0, stream,
            x, w1b, ffn1, DH, DM, TOK / BM, DH / BN, eA1, eB1, eC1);
        hipLaunchKernelGGL((gemm2<0, 2, false, false>), g2, blk, 0, stream,
            ffn1, w2, out, DM, DH, TOK / BM, DM / BN, eA2, eB2, eC2);
    } else if (ws_size >= SZ_F) {
        const dim3 g1(EXPERTS * (TOK / BM) * (DH / BN));
        const dim3 g2(EXPERTS * (TOK / BM) * (DM / BN));
        hipLaunchKernelGGL((gemm2<2, 2, true, true>), g1, blk, 0, stream,
            x, w1, ffn1, DH, DM, TOK / BM, DH / BN, eA1, eB1, eC1);
        hipLaunchKernelGGL((gemm2<0, 2, false, false>), g2, blk, 0, stream,
            ffn1, w2, out, DM, DH, TOK / BM, DM / BN, eA2, eB2, eC2);
    } else {
        int rows = (int)((ws_size / ((size_t)DH * sizeof(__bf16))) / BM) * BM;
        if (rows <= 0) rows = BM;
        if (rows > TOK) rows = TOK;
        for (int e = 0; e < EXPERTS; ++e) {
            for (int r0 = 0; r0 < TOK; r0 += rows) {
                int mr = (TOK - r0 < rows) ? (TOK - r0) : rows;
                dim3 cg1((mr / BM) * (DH / BN));
                hipLaunchKernelGGL((gemm2<2, 2, true, true>), cg1, blk, 0, stream,
                    x + ((size_t)e * TOK + r0) * DM, w1 + (size_t)e * DH * DM, ffn1,
                    DH, DM, mr / BM, DH / BN, (size_t)0, (size_t)0, (size_t)0);
                dim3 cg2((mr / BM) * (DM / BN));
                hipLaunchKernelGGL((gemm2<0, 2, false, false>), cg2, blk, 0, stream,
                    ffn1, w2 + (size_t)e * DM * DH, out + ((size_t)e * TOK + r0) * DM,
                    DM, DH, mr / BM, DM / BN, (size_t)0, (size_t)0, (size_t)0);
            }
        }
    }
}

// Round 5
// 349.458 us; speedup vs baseline: 1.7023x; 1.0430x over previous
//
#include <hip/hip_runtime.h>
#include <hip/hip_bf16.h>

#define EXPERTS 8
#define TOK 2048
#define DM 1024
#define DH 4096

#define BM 128
#define BN 128
#define BK 32
#define LSTR 40

typedef __bf16 bf16x8 __attribute__((ext_vector_type(8)));
typedef float  f32x4  __attribute__((ext_vector_type(4)));

static __device__ __forceinline__ bf16x8 cvt8(float4 a, float4 b) {
    bf16x8 r;
    r[0] = (__bf16)a.x; r[1] = (__bf16)a.y; r[2] = (__bf16)a.z; r[3] = (__bf16)a.w;
    r[4] = (__bf16)b.x; r[5] = (__bf16)b.y; r[6] = (__bf16)b.z; r[7] = (__bf16)b.w;
    return r;
}

static __device__ __forceinline__ void gload16(const __bf16* g, __bf16* l) {
    __builtin_amdgcn_global_load_lds(
        (__attribute__((address_space(1))) void*)g,
        (__attribute__((address_space(3))) void*)l, 16, 0, 0);
}

#define BARRIER() asm volatile("s_barrier" ::: "memory")
#define LGKM0()   do { asm volatile("s_waitcnt lgkmcnt(0)" ::: "memory"); \
                       __builtin_amdgcn_sched_barrier(0); } while (0)
#define LGKM8()   asm volatile("s_waitcnt lgkmcnt(8)" ::: "memory")
#define VMW4()    asm volatile("s_waitcnt vmcnt(4)" ::: "memory")
#define VMW0()    asm volatile("s_waitcnt vmcnt(0)" ::: "memory")

// single fused fp32->bf16 convert for x, w1, w2 (one launch)
__global__ __launch_bounds__(256)
void cvt_all(const float* __restrict__ x,  const float* __restrict__ w1,
             const float* __restrict__ w2, __bf16* __restrict__ xb,
             __bf16* __restrict__ w1b,     __bf16* __restrict__ w2b,
             int nx, int nw1, int ntot) {
    int i = blockIdx.x * blockDim.x + threadIdx.x;
    const int stride = gridDim.x * blockDim.x;
    for (; i < ntot; i += stride) {
        const float* src; __bf16* dst; int off;
        if (i < nx)            { src = x;  dst = xb;  off = i; }
        else if (i < nx + nw1) { src = w1; dst = w1b; off = i - nx; }
        else                   { src = w2; dst = w2b; off = i - nx - nw1; }
        const float4* p = (const float4*)src + (size_t)off * 2;
        float4 a = p[0], b = p[1];
        *((bf16x8*)dst + off) = cvt8(a, b);
    }
}

// ------------- 256x256 8-phase bf16 GEMM (C = A * B^T), m201 schedule -------
// 8 waves (2Mx4N), per-wave 128x64 out, BK=64, 2 K-tiles per outer iter.
// buf0 holds even K-tiles, buf1 odd. Per phase: {ds_read subtile || stage 1
// half (2 gloads) -> barrier -> lgkmcnt(0) -> 16 MFMA -> barrier}. vmcnt(4)
// only at ends of P3/P7. Stage placement (region free after the barrier
// following its last reader's phase):
//   P0:A0(2it+1) P1:A1(2it+1) P2:B0(2it+2) P3:B1(2it+2)
//   P4:A0(2it+2) P5:A1(2it+2) P6:B0(2it+3) P7:B1(2it+3)
template<bool RELU, bool OUT_BF16>
__global__ __launch_bounds__(512, 2)
void gemm8(const __bf16* __restrict__ Ap, const __bf16* __restrict__ Bp,
           void* __restrict__ Cp, int N, int K, int tiles_m, int tiles_n,
           size_t sA, size_t sB, size_t sC)
{
    __shared__ __bf16 lds[2][2][16384];   // [buf][A/B][256*64] = 128 KiB

    int bid = blockIdx.x;                 // grid % 8 == 0 for all launches
    const int chunk = gridDim.x >> 3;
    bid = (bid & 7) * chunk + (bid >> 3);

    const int per_e = tiles_m * tiles_n;
    const int e  = bid / per_e;
    const int tt = bid - e * per_e;
    const int tn = tt / tiles_m;          // consecutive blocks share B panel
    const int tm = tt - tn * tiles_m;

    const int tid = threadIdx.x;
    const int l   = tid & 63;
    const int wid = tid >> 6;             // 0..7
    const int wr  = wid >> 2;             // 0..1
    const int wc  = wid & 3;              // 0..3
    const int lr  = l & 15;
    const int kg  = l >> 4;               // 0..3
    const int lq  = l >> 3;               // 0..7
    const int swz_e = ((l & 7) ^ lq) << 3;        // staging src swizzle (elems)

    const int cc0  = (kg * 16) ^ ((l & 7) << 4);  // ds_read col byte, kstep 0
    const int cc1  = cc0 ^ 64;                    // kstep 1
    const int rowA = (wr * 128 + lr) * 128;
    const int rowB = (wc * 64  + lr) * 128;

    const __bf16* Ag = Ap + e * sA + (size_t)(tm * 256) * K;
    const __bf16* Bg = Bp + e * sB + (size_t)(tn * 256) * K;

    // stage half h (128 rows x 64 cols) of matrix mat, K-tile kt2, buffer c2
    auto stage_half = [&](const __bf16* g, int mat, int c2, int h, int kt2) {
        const __bf16* s0 = g + (size_t)(h * 128 + wid * 8 + lq) * K + kt2 * 64 + swz_e;
        gload16(s0,                  &lds[c2][mat][h * 8192 + wid * 512]);
        gload16(s0 + (size_t)64 * K, &lds[c2][mat][h * 8192 + 4096 + wid * 512]);
    };

    f32x4 acc[8][4];
    #pragma unroll
    for (int m = 0; m < 8; ++m)
        #pragma unroll
        for (int n = 0; n < 4; ++n)
            acc[m][n] = (f32x4){0.f, 0.f, 0.f, 0.f};

    const char* A0b = (const char*)&lds[0][0][0] + rowA;
    const char* B0b = (const char*)&lds[0][1][0] + rowB;
    const char* A1b = (const char*)&lds[1][0][0] + rowA;
    const char* B1b = (const char*)&lds[1][1][0] + rowB;

    bf16x8 al[4][2], ah[4][2], bl[2][2], bh[2][2];

    auto rdA = [&](bf16x8 (&dst)[4][2], const char* base, int half) {
        #pragma unroll
        for (int mf = 0; mf < 4; ++mf) {
            dst[mf][0] = *(const bf16x8*)(base + (half * 4 + mf) * 2048 + cc0);
            dst[mf][1] = *(const bf16x8*)(base + (half * 4 + mf) * 2048 + cc1);
        }
    };
    auto rdB = [&](bf16x8 (&dst)[2][2], const char* base, int half) {
        #pragma unroll
        for (int nf = 0; nf < 2; ++nf) {
            dst[nf][0] = *(const bf16x8*)(base + (half * 2 + nf) * 2048 + cc0);
            dst[nf][1] = *(const bf16x8*)(base + (half * 2 + nf) * 2048 + cc1);
        }
    };
    auto mma16 = [&](bf16x8 (&af)[4][2], bf16x8 (&bf_)[2][2], int mo, int no) {
        __builtin_amdgcn_s_setprio(1);
        #pragma unroll
        for (int mf = 0; mf < 4; ++mf)
            #pragma unroll
            for (int nf = 0; nf < 2; ++nf) {
                acc[mo + mf][no + nf] = __builtin_amdgcn_mfma_f32_16x16x32_bf16(af[mf][0], bf_[nf][0], acc[mo + mf][no + nf], 0, 0, 0);
                acc[mo + mf][no + nf] = __builtin_amdgcn_mfma_f32_16x16x32_bf16(af[mf][1], bf_[nf][1], acc[mo + mf][no + nf], 0, 0, 0);
            }
        __builtin_amdgcn_s_setprio(0);
    };

    const int NT = K / 64;                // even for all our launches
    const int NI = NT / 2;

    // Prologue: tile 0 fully (4 halves), then tile 1's B halves.
    stage_half(Ag, 0, 0, 0, 0); stage_half(Ag, 0, 0, 1, 0);
    stage_half(Bg, 1, 0, 0, 0); stage_half(Bg, 1, 0, 1, 0);
    stage_half(Bg, 1, 1, 0, 1); stage_half(Bg, 1, 1, 1, 1);
    VMW4();                               // tile 0 landed; tile 1 B in flight
    BARRIER();

    for (int it = 0; it < NI; ++it) {
        const int To = 2 * it + 1;        // odd tile this iter
        const int Te = 2 * it + 2;        // next even tile
        const int Tn = 2 * it + 3;        // next odd tile
        const bool pf = (it + 1 < NI);

        // ---- P0: read a_lo,b_lo (tile 2it, buf0); stage A0(To -> buf1)
        rdA(al, A0b, 0); rdB(bl, B0b, 0);
        stage_half(Ag, 0, 1, 0, To);
        LGKM8();
        BARRIER(); LGKM0();
        mma16(al, bl, 0, 0);
        BARRIER();

        // ---- P1: read b_hi; stage A1(To -> buf1)
        rdB(bh, B0b, 1);
        stage_half(Ag, 0, 1, 1, To);
        BARRIER(); LGKM0();
        mma16(al, bh, 0, 2);
        BARRIER();

        // ---- P2: read a_hi; stage B0(Te -> buf0)
        rdA(ah, A0b, 1);
        if (pf) stage_half(Bg, 1, 0, 0, Te);
        BARRIER(); LGKM0();
        mma16(ah, bh, 4, 2);
        BARRIER();

        // ---- P3: no reads; stage B1(Te -> buf0)
        if (pf) stage_half(Bg, 1, 0, 1, Te);
        BARRIER();
        mma16(ah, bl, 4, 0);
        if (pf) VMW4(); else VMW0();      // tile To fully landed
        BARRIER();

        // ---- P4: read a_lo,b_lo (tile To, buf1); stage A0(Te -> buf0)
        rdA(al, A1b, 0); rdB(bl, B1b, 0);
        if (pf) stage_half(Ag, 0, 0, 0, Te);
        LGKM8();
        BARRIER(); LGKM0();
        mma16(al, bl, 0, 0);
        BARRIER();

        // ---- P5: read b_hi; stage A1(Te -> buf0)
        rdB(bh, B1b, 1);
        if (pf) stage_half(Ag, 0, 0, 1, Te);
        BARRIER(); LGKM0();
        mma16(al, bh, 0, 2);
        BARRIER();

        // ---- P6: read a_hi; stage B0(Tn -> buf1)
        rdA(ah, A1b, 1);
        if (pf) stage_half(Bg, 1, 1, 0, Tn);
        BARRIER(); LGKM0();
        mma16(ah, bh, 4, 2);
        BARRIER();

        // ---- P7: no reads; stage B1(Tn -> buf1)
        if (pf) stage_half(Bg, 1, 1, 1, Tn);
        BARRIER();
        mma16(ah, bl, 4, 0);
        if (pf) VMW4();                   // tile Te fully landed
        BARRIER();
    }

    // Epilogue. C/D: col = lane&15, row = (lane>>4)*4 + reg.
    const int orow = tm * 256 + wr * 128 + kg * 4;
    const int ocol = tn * 256 + wc * 64 + lr;
    if constexpr (OUT_BF16) {
        __bf16* C = (__bf16*)Cp + e * sC;
        #pragma unroll
        for (int mf = 0; mf < 8; ++mf)
            #pragma unroll
            for (int j = 0; j < 4; ++j) {
                const size_t base = (size_t)(orow + mf * 16 + j) * N + ocol;
                #pragma unroll
                for (int nf = 0; nf < 4; ++nf) {
                    float v = acc[mf][nf][j];
                    if (RELU) v = fmaxf(v, 0.f);
                    C[base + nf * 16] = (__bf16)v;
                }
            }
    } else {
        float* C = (float*)Cp + e * sC;
        #pragma unroll
        for (int mf = 0; mf < 8; ++mf)
            #pragma unroll
            for (int j = 0; j < 4; ++j) {
                const size_t base = (size_t)(orow + mf * 16 + j) * N + ocol;
                #pragma unroll
                for (int nf = 0; nf < 4; ++nf) {
                    float v = acc[mf][nf][j];
                    if (RELU) v = fmaxf(v, 0.f);
                    C[base + nf * 16] = v;
                }
            }
    }
}

// ---------------- fallback 128x128 kernel (tiers B-E) ----------------
template<int AMODE, int BMODE, bool RELU, bool OUT_BF16>
__global__ __launch_bounds__(256)
void gemm2(const void* __restrict__ Ap, const void* __restrict__ Bp,
           void* __restrict__ Cp, int N, int K, int tiles_m, int tiles_n,
           size_t sA, size_t sB, size_t sC)
{
    constexpr int LA = (AMODE == 0) ? BK : LSTR;
    constexpr int LB = (BMODE == 0) ? BK : LSTR;
    __shared__ __bf16 As[BM * LA];
    __shared__ __bf16 Bs[BN * LB];

    int bid = blockIdx.x;
    const int chunk = gridDim.x >> 3;
    bid = (bid & 7) * chunk + (bid >> 3);

    const int per_e = tiles_m * tiles_n;
    const int e  = bid / per_e;
    const int t  = bid - e * per_e;
    const int tn = t / tiles_m;
    const int tm = t - tn * tiles_m;

    const int tid = threadIdx.x;
    const int l   = tid & 63;
    const int wid = tid >> 6;
    const int wr  = wid >> 1, wc = wid & 1;
    const int lr  = l & 15;
    const int kg  = l >> 4;
    const int srow = tid >> 1;
    const int scol = (tid & 1) << 4;

    const __bf16* gA = nullptr; __bf16* lA = nullptr;
    const float*  pAf = nullptr; __bf16* aWr = nullptr;
    float4 A0, A1, A2, A3;
    if constexpr (AMODE == 0) {
        gA = (const __bf16*)Ap + e * sA
           + (size_t)(tm * BM + wid * 16 + (l >> 2)) * K + (l & 3) * 8;
        lA = As + wid * 512;
    } else {
        pAf = (const float*)Ap + e * sA + (size_t)(tm * BM + srow) * K + scol;
        aWr = As + srow * LA + scol;
        A0 = *(const float4*)(pAf);      A1 = *(const float4*)(pAf + 4);
        A2 = *(const float4*)(pAf + 8);  A3 = *(const float4*)(pAf + 12);
    }
    const __bf16* gB = nullptr; __bf16* lB = nullptr;
    const float*  pBf = nullptr; __bf16* bWr = nullptr;
    float4 B0, B1, B2, B3;
    if constexpr (BMODE == 0) {
        gB = (const __bf16*)Bp + e * sB
           + (size_t)(tn * BN + wid * 16 + (l >> 2)) * K + (l & 3) * 8;
        lB = Bs + wid * 512;
    } else {
        pBf = (const float*)Bp + e * sB + (size_t)(tn * BN + srow) * K + scol;
        bWr = Bs + srow * LB + scol;
        B0 = *(const float4*)(pBf);      B1 = *(const float4*)(pBf + 4);
        B2 = *(const float4*)(pBf + 8);  B3 = *(const float4*)(pBf + 12);
    }

    const __bf16* aRd = As + (wr * 64 + lr) * LA + kg * 8;
    const __bf16* bRd = Bs + (wc * 64 + lr) * LB + kg * 8;

    f32x4 acc[4][4];
    #pragma unroll
    for (int m = 0; m < 4; ++m)
        #pragma unroll
        for (int n = 0; n < 4; ++n)
            acc[m][n] = (f32x4){0.f, 0.f, 0.f, 0.f};

    const int NT = K / BK;
    for (int kt = 0; kt < NT; ++kt) {
        if (kt) __syncthreads();
        if constexpr (AMODE == 0) {
            gload16(gA, lA);
            gload16(gA + (size_t)64 * K, lA + 2048);
            gA += BK;
        } else {
            *(bf16x8*)(aWr)     = cvt8(A0, A1);
            *(bf16x8*)(aWr + 8) = cvt8(A2, A3);
        }
        if constexpr (BMODE == 0) {
            gload16(gB, lB);
            gload16(gB + (size_t)64 * K, lB + 2048);
            gB += BK;
        } else {
            *(bf16x8*)(bWr)     = cvt8(B0, B1);
            *(bf16x8*)(bWr + 8) = cvt8(B2, B3);
        }
        __syncthreads();

        if (kt + 1 < NT) {
            if constexpr (AMODE == 2) {
                pAf += BK;
                A0 = *(const float4*)(pAf);      A1 = *(const float4*)(pAf + 4);
                A2 = *(const float4*)(pAf + 8);  A3 = *(const float4*)(pAf + 12);
            }
            if constexpr (BMODE == 2) {
                pBf += BK;
                B0 = *(const float4*)(pBf);      B1 = *(const float4*)(pBf + 4);
                B2 = *(const float4*)(pBf + 8);  B3 = *(const float4*)(pBf + 12);
            }
        }

        bf16x8 af[4], bfr[4];
        #pragma unroll
        for (int m = 0; m < 4; ++m) af[m]  = *(const bf16x8*)(aRd + m * 16 * LA);
        #pragma unroll
        for (int n = 0; n < 4; ++n) bfr[n] = *(const bf16x8*)(bRd + n * 16 * LB);
        #pragma unroll
        for (int m = 0; m < 4; ++m)
            #pragma unroll
            for (int n = 0; n < 4; ++n)
                acc[m][n] = __builtin_amdgcn_mfma_f32_16x16x32_bf16(af[m], bfr[n], acc[m][n], 0, 0, 0);
    }

    const int orow = tm * BM + wr * 64 + kg * 4;
    const int ocol = tn * BN + wc * 64 + lr;
    if constexpr (OUT_BF16) {
        __bf16* C = (__bf16*)Cp + e * sC;
        #pragma unroll
        for (int m = 0; m < 4; ++m)
            #pragma unroll
            for (int j = 0; j < 4; ++j) {
                const size_t base = (size_t)(orow + m * 16 + j) * N + ocol;
                #pragma unroll
                for (int n = 0; n < 4; ++n) {
                    float v = acc[m][n][j];
                    if (RELU) v = fmaxf(v, 0.f);
                    C[base + n * 16] = (__bf16)v;
                }
            }
    } else {
        float* C = (float*)Cp + e * sC;
        #pragma unroll
        for (int m = 0; m < 4; ++m)
            #pragma unroll
            for (int j = 0; j < 4; ++j) {
                const size_t base = (size_t)(orow + m * 16 + j) * N + ocol;
                #pragma unroll
                for (int n = 0; n < 4; ++n) {
                    float v = acc[m][n][j];
                    if (RELU) v = fmaxf(v, 0.f);
                    C[base + n * 16] = v;
                }
            }
    }
}

extern "C" void kernel_launch(void* const* d_in, const int* in_sizes, int n_in,
                              void* d_out, int out_size, void* d_ws, size_t ws_size,
                              hipStream_t stream) {
    const float* x  = (const float*)d_in[0];   // [8, 2048, 1024]
    const float* w1 = (const float*)d_in[1];   // [8, 4096, 1024]
    const float* w2 = (const float*)d_in[2];   // [8, 1024, 4096]
    float* out = (float*)d_out;                // [8, 2048, 1024]

    const size_t SZ_F  = (size_t)EXPERTS * TOK * DH * sizeof(__bf16);  // 134.2 MB
    const size_t SZ_X  = (size_t)EXPERTS * TOK * DM * sizeof(__bf16);
    const size_t SZ_W1 = (size_t)EXPERTS * DH * DM * sizeof(__bf16);
    const size_t SZ_W2 = (size_t)EXPERTS * DM * DH * sizeof(__bf16);

    char* wsb = (char*)d_ws;
    __bf16* ffn1 = (__bf16*)wsb;

    const dim3 blk(256);
    const dim3 cgrid(2048);
    const int NX  = EXPERTS * TOK * DM / 8;
    const int NW1 = EXPERTS * DH * DM / 8;
    const int NW2 = EXPERTS * DM * DH / 8;

    const size_t eA1 = (size_t)TOK * DM, eB1 = (size_t)DH * DM, eC1 = (size_t)TOK * DH;
    const size_t eA2 = (size_t)TOK * DH, eB2 = (size_t)DM * DH, eC2 = (size_t)TOK * DM;

    if (ws_size >= SZ_F + SZ_X + SZ_W1 + SZ_W2) {
        // Tier A: fused cvt, then both GEMMs on the 8-phase 256x256 kernel
        __bf16* xb  = (__bf16*)(wsb + SZ_F);
        __bf16* w1b = (__bf16*)(wsb + SZ_F + SZ_X);
        __bf16* w2b = (__bf16*)(wsb + SZ_F + SZ_X + SZ_W1);
        hipLaunchKernelGGL(cvt_all, cgrid, blk, 0, stream,
            x, w1, w2, xb, w1b, w2b, NX, NW1, NX + NW1 + NW2);
        const dim3 g1(EXPERTS * (TOK / 256) * (DH / 256));   // 1024
        const dim3 g2(EXPERTS * (TOK / 256) * (DM / 256));   // 256
        hipLaunchKernelGGL((gemm8<true, true>), g1, dim3(512), 0, stream,
            xb, w1b, ffn1, DH, DM, TOK / 256, DH / 256, eA1, eB1, eC1);
        hipLaunchKernelGGL((gemm8<false, false>), g2, dim3(512), 0, stream,
            ffn1, w2b, out, DM, DH, TOK / 256, DM / 256, eA2, eB2, eC2);
    } else if (ws_size >= SZ_F + SZ_X + SZ_W1) {
        __bf16* xb  = (__bf16*)(wsb + SZ_F);
        __bf16* w1b = (__bf16*)(wsb + SZ_F + SZ_X);
        hipLaunchKernelGGL(cvt_all, cgrid, blk, 0, stream,
            x, w1, w1, xb, w1b, w1b, NX, NW1, NX + NW1);
        const dim3 g1(EXPERTS * (TOK / 256) * (DH / 256));
        const dim3 g2(EXPERTS * (TOK / BM) * (DM / BN));
        hipLaunchKernelGGL((gemm8<true, true>), g1, dim3(512), 0, stream,
            xb, w1b, ffn1, DH, DM, TOK / 256, DH / 256, eA1, eB1, eC1);
        hipLaunchKernelGGL((gemm2<0, 2, false, false>), g2, blk, 0, stream,
            ffn1, w2, out, DM, DH, TOK / BM, DM / BN, eA2, eB2, eC2);
    } else if (ws_size >= SZ_F + SZ_W1) {
        __bf16* w1b = (__bf16*)(wsb + SZ_F);
        hipLaunchKernelGGL(cvt_all, cgrid, blk, 0, stream,
            w1, w1, w1, w1b, w1b, w1b, NW1, 0, NW1);
        const dim3 g1(EXPERTS * (TOK / BM) * (DH / BN));
        const dim3 g2(EXPERTS * (TOK / BM) * (DM / BN));
        hipLaunchKernelGGL((gemm2<2, 0, true, true>), g1, blk, 0, stream,
            x, w1b, ffn1, DH, DM, TOK / BM, DH / BN, eA1, eB1, eC1);
        hipLaunchKernelGGL((gemm2<0, 2, false, false>), g2, blk, 0, stream,
            ffn1, w2, out, DM, DH, TOK / BM, DM / BN, eA2, eB2, eC2);
    } else if (ws_size >= SZ_F) {
        const dim3 g1(EXPERTS * (TOK / BM) * (DH / BN));
        const dim3 g2(EXPERTS * (TOK / BM) * (DM / BN));
        hipLaunchKernelGGL((gemm2<2, 2, true, true>), g1, blk, 0, stream,
            x, w1, ffn1, DH, DM, TOK / BM, DH / BN, eA1, eB1, eC1);
        hipLaunchKernelGGL((gemm2<0, 2, false, false>), g2, blk, 0, stream,
            ffn1, w2, out, DM, DH, TOK / BM, DM / BN, eA2, eB2, eC2);
    } else {
        int rows = (int)((ws_size / ((size_t)DH * sizeof(__bf16))) / BM) * BM;
        if (rows <= 0) rows = BM;
        if (rows > TOK) rows = TOK;
        for (int e = 0; e < EXPERTS; ++e) {
            for (int r0 = 0; r0 < TOK; r0 += rows) {
                int mr = (TOK - r0 < rows) ? (TOK - r0) : rows;
                dim3 cg1((mr / BM) * (DH / BN));
                hipLaunchKernelGGL((gemm2<2, 2, true, true>), cg1, blk, 0, stream,
                    x + ((size_t)e * TOK + r0) * DM, w1 + (size_t)e * DH * DM, ffn1,
                    DH, DM, mr / BM, DH / BN, (size_t)0, (size_t)0, (size_t)0);
                dim3 cg2((mr / BM) * (DM / BN));
                hipLaunchKernelGGL((gemm2<0, 2, false, false>), cg2, blk, 0, stream,
                    ffn1, w2 + (size_t)e * DM * DH, out + ((size_t)e * TOK + r0) * DM,
                    DM, DH, mr / BM, DM / BN, (size_t)0, (size_t)0, (size_t)0);
            }
        }
    }
}

// Round 6
// 345.215 us; speedup vs baseline: 1.7232x; 1.0123x over previous
//
#include <hip/hip_runtime.h>
#include <hip/hip_bf16.h>

#define EXPERTS 8
#define TOK 2048
#define DM 1024
#define DH 4096

#define BM 128
#define BN 128
#define BK 32
#define LSTR 40

typedef __bf16 bf16x8 __attribute__((ext_vector_type(8)));
typedef float  f32x4  __attribute__((ext_vector_type(4)));

static __device__ __forceinline__ bf16x8 cvt8(float4 a, float4 b) {
    bf16x8 r;
    r[0] = (__bf16)a.x; r[1] = (__bf16)a.y; r[2] = (__bf16)a.z; r[3] = (__bf16)a.w;
    r[4] = (__bf16)b.x; r[5] = (__bf16)b.y; r[6] = (__bf16)b.z; r[7] = (__bf16)b.w;
    return r;
}

static __device__ __forceinline__ void gload16(const __bf16* g, __bf16* l) {
    __builtin_amdgcn_global_load_lds(
        (__attribute__((address_space(1))) void*)g,
        (__attribute__((address_space(3))) void*)l, 16, 0, 0);
}

#define BARRIER() asm volatile("s_barrier" ::: "memory")
#define SB()      __builtin_amdgcn_sched_barrier(0)
#define LGKM0()   do { asm volatile("s_waitcnt lgkmcnt(0)" ::: "memory"); SB(); } while (0)
#define LGKM2()   do { asm volatile("s_waitcnt lgkmcnt(2)" ::: "memory"); SB(); } while (0)
#define LGKM4()   do { asm volatile("s_waitcnt lgkmcnt(4)" ::: "memory"); SB(); } while (0)
#define LGKM6()   do { asm volatile("s_waitcnt lgkmcnt(6)" ::: "memory"); SB(); } while (0)
#define VMW4()    asm volatile("s_waitcnt vmcnt(4)" ::: "memory")
#define VMW0()    asm volatile("s_waitcnt vmcnt(0)" ::: "memory")

// single fused fp32->bf16 convert for x, w1, w2 (one launch)
__global__ __launch_bounds__(256)
void cvt_all(const float* __restrict__ x,  const float* __restrict__ w1,
             const float* __restrict__ w2, __bf16* __restrict__ xb,
             __bf16* __restrict__ w1b,     __bf16* __restrict__ w2b,
             int nx, int nw1, int ntot) {
    int i = blockIdx.x * blockDim.x + threadIdx.x;
    const int stride = gridDim.x * blockDim.x;
    for (; i < ntot; i += stride) {
        const float* src; __bf16* dst; int off;
        if (i < nx)            { src = x;  dst = xb;  off = i; }
        else if (i < nx + nw1) { src = w1; dst = w1b; off = i - nx; }
        else                   { src = w2; dst = w2b; off = i - nx - nw1; }
        const float4* p = (const float4*)src + (size_t)off * 2;
        float4 a = p[0], b = p[1];
        *((bf16x8*)dst + off) = cvt8(a, b);
    }
}

// ------------- 256x256 8-phase bf16 GEMM (C = A * B^T), kk-split -----------
// 8 waves (2Mx4N), per-wave 128x64 out, BK=64, 2 K-tiles per outer iter.
// buf0 even K-tiles, buf1 odd. Per phase: {issue kk0 reads | SB | issue kk1
// reads | stage 1 half -> barrier -> lgkmcnt(NR/2) -> 8 MFMA kk0 (kk1 reads
// drain under them) -> lgkmcnt(0) -> 8 MFMA kk1 -> barrier}. All reads
// complete before the closing barrier => region retirement identical to the
// verified round-5 schedule. vmcnt(4) only at P3/P7. Stage placement:
//   P0:A0(2it+1) P1:A1(2it+1) P2:B0(2it+2) P3:B1(2it+2)
//   P4:A0(2it+2) P5:A1(2it+2) P6:B0(2it+3) P7:B1(2it+3)
template<bool RELU, bool OUT_BF16>
__global__ __launch_bounds__(512, 2)
void gemm8(const __bf16* __restrict__ Ap, const __bf16* __restrict__ Bp,
           void* __restrict__ Cp, int N, int K, int tiles_m, int tiles_n,
           size_t sA, size_t sB, size_t sC)
{
    __shared__ __bf16 lds[2][2][16384];   // [buf][A/B][256*64] = 128 KiB

    int bid = blockIdx.x;                 // grid % 8 == 0 for all launches
    const int chunk = gridDim.x >> 3;
    bid = (bid & 7) * chunk + (bid >> 3);

    const int per_e = tiles_m * tiles_n;
    const int e  = bid / per_e;
    const int tt = bid - e * per_e;
    const int tn = tt / tiles_m;          // consecutive blocks share B panel
    const int tm = tt - tn * tiles_m;

    const int tid = threadIdx.x;
    const int l   = tid & 63;
    const int wid = tid >> 6;             // 0..7
    const int wr  = wid >> 2;             // 0..1
    const int wc  = wid & 3;              // 0..3
    const int lr  = l & 15;
    const int kg  = l >> 4;               // 0..3
    const int lq  = l >> 3;               // 0..7
    const int swz_e = ((l & 7) ^ lq) << 3;        // staging src swizzle (elems)

    const int cc0  = (kg * 16) ^ ((l & 7) << 4);  // ds_read col byte, kstep 0
    const int cc1  = cc0 ^ 64;                    // kstep 1
    const int rowA = (wr * 128 + lr) * 128;
    const int rowB = (wc * 64  + lr) * 128;

    const __bf16* Ag = Ap + e * sA + (size_t)(tm * 256) * K;
    const __bf16* Bg = Bp + e * sB + (size_t)(tn * 256) * K;

    // stage half h (128 rows x 64 cols) of matrix mat, K-tile kt2, buffer c2
    auto stage_half = [&](const __bf16* g, int mat, int c2, int h, int kt2) {
        const __bf16* s0 = g + (size_t)(h * 128 + wid * 8 + lq) * K + kt2 * 64 + swz_e;
        gload16(s0,                  &lds[c2][mat][h * 8192 + wid * 512]);
        gload16(s0 + (size_t)64 * K, &lds[c2][mat][h * 8192 + 4096 + wid * 512]);
    };

    f32x4 acc[8][4];
    #pragma unroll
    for (int m = 0; m < 8; ++m)
        #pragma unroll
        for (int n = 0; n < 4; ++n)
            acc[m][n] = (f32x4){0.f, 0.f, 0.f, 0.f};

    const char* A0b = (const char*)&lds[0][0][0] + rowA;
    const char* B0b = (const char*)&lds[0][1][0] + rowB;
    const char* A1b = (const char*)&lds[1][0][0] + rowA;
    const char* B1b = (const char*)&lds[1][1][0] + rowB;

    bf16x8 al[4][2], ah[4][2], bl[2][2], bh[2][2];

    // one K-half of a fragment set (static kk index -> no scratch)
    auto rdA_k = [&](bf16x8 (&dst)[4][2], const char* base, int half, int kk) {
        const int cc = kk ? cc1 : cc0;
        #pragma unroll
        for (int mf = 0; mf < 4; ++mf)
            dst[mf][kk] = *(const bf16x8*)(base + (half * 4 + mf) * 2048 + cc);
    };
    auto rdB_k = [&](bf16x8 (&dst)[2][2], const char* base, int half, int kk) {
        const int cc = kk ? cc1 : cc0;
        #pragma unroll
        for (int nf = 0; nf < 2; ++nf)
            dst[nf][kk] = *(const bf16x8*)(base + (half * 2 + nf) * 2048 + cc);
    };
    auto mma8 = [&](bf16x8 (&af)[4][2], bf16x8 (&bf_)[2][2], int mo, int no, int kk) {
        __builtin_amdgcn_s_setprio(1);
        #pragma unroll
        for (int mf = 0; mf < 4; ++mf)
            #pragma unroll
            for (int nf = 0; nf < 2; ++nf)
                acc[mo + mf][no + nf] = __builtin_amdgcn_mfma_f32_16x16x32_bf16(
                    af[mf][kk], bf_[nf][kk], acc[mo + mf][no + nf], 0, 0, 0);
        __builtin_amdgcn_s_setprio(0);
    };

    const int NT = K / 64;                // even for all our launches
    const int NI = NT / 2;

    // Prologue: tile 0 fully (4 halves), then tile 1's B halves.
    stage_half(Ag, 0, 0, 0, 0); stage_half(Ag, 0, 0, 1, 0);
    stage_half(Bg, 1, 0, 0, 0); stage_half(Bg, 1, 0, 1, 0);
    stage_half(Bg, 1, 1, 0, 1); stage_half(Bg, 1, 1, 1, 1);
    VMW4();                               // tile 0 landed; tile 1 B in flight
    BARRIER();

    for (int it = 0; it < NI; ++it) {
        const int To = 2 * it + 1;        // odd tile this iter
        const int Te = 2 * it + 2;        // next even tile
        const int Tn = 2 * it + 3;        // next odd tile
        const bool pf = (it + 1 < NI);

        // ---- P0: al+bl (12 reads, kk-split); stage A0(To -> buf1)
        rdA_k(al, A0b, 0, 0); rdB_k(bl, B0b, 0, 0);
        SB();
        rdA_k(al, A0b, 0, 1); rdB_k(bl, B0b, 0, 1);
        stage_half(Ag, 0, 1, 0, To);
        BARRIER();
        LGKM6();
        mma8(al, bl, 0, 0, 0);
        LGKM0();
        mma8(al, bl, 0, 0, 1);
        BARRIER();

        // ---- P1: bh (4 reads); stage A1(To -> buf1)
        rdB_k(bh, B0b, 1, 0);
        SB();
        rdB_k(bh, B0b, 1, 1);
        stage_half(Ag, 0, 1, 1, To);
        BARRIER();
        LGKM2();
        mma8(al, bh, 0, 2, 0);
        LGKM0();
        mma8(al, bh, 0, 2, 1);
        BARRIER();

        // ---- P2: ah (8 reads); stage B0(Te -> buf0)
        rdA_k(ah, A0b, 1, 0);
        SB();
        rdA_k(ah, A0b, 1, 1);
        if (pf) stage_half(Bg, 1, 0, 0, Te);
        BARRIER();
        LGKM4();
        mma8(ah, bh, 4, 2, 0);
        LGKM0();
        mma8(ah, bh, 4, 2, 1);
        BARRIER();

        // ---- P3: no reads; stage B1(Te -> buf0)
        if (pf) stage_half(Bg, 1, 0, 1, Te);
        BARRIER();
        mma8(ah, bl, 4, 0, 0);
        mma8(ah, bl, 4, 0, 1);
        if (pf) VMW4(); else VMW0();      // tile To fully landed
        BARRIER();

        // ---- P4: al+bl (tile To, buf1); stage A0(Te -> buf0)
        rdA_k(al, A1b, 0, 0); rdB_k(bl, B1b, 0, 0);
        SB();
        rdA_k(al, A1b, 0, 1); rdB_k(bl, B1b, 0, 1);
        if (pf) stage_half(Ag, 0, 0, 0, Te);
        BARRIER();
        LGKM6();
        mma8(al, bl, 0, 0, 0);
        LGKM0();
        mma8(al, bl, 0, 0, 1);
        BARRIER();

        // ---- P5: bh; stage A1(Te -> buf0)
        rdB_k(bh, B1b, 1, 0);
        SB();
        rdB_k(bh, B1b, 1, 1);
        if (pf) stage_half(Ag, 0, 0, 1, Te);
        BARRIER();
        LGKM2();
        mma8(al, bh, 0, 2, 0);
        LGKM0();
        mma8(al, bh, 0, 2, 1);
        BARRIER();

        // ---- P6: ah; stage B0(Tn -> buf1)
        rdA_k(ah, A1b, 1, 0);
        SB();
        rdA_k(ah, A1b, 1, 1);
        if (pf) stage_half(Bg, 1, 1, 0, Tn);
        BARRIER();
        LGKM4();
        mma8(ah, bh, 4, 2, 0);
        LGKM0();
        mma8(ah, bh, 4, 2, 1);
        BARRIER();

        // ---- P7: no reads; stage B1(Tn -> buf1)
        if (pf) stage_half(Bg, 1, 1, 1, Tn);
        BARRIER();
        mma8(ah, bl, 4, 0, 0);
        mma8(ah, bl, 4, 0, 1);
        if (pf) VMW4();                   // tile Te fully landed
        BARRIER();
    }

    // Epilogue. C/D: col = lane&15, row = (lane>>4)*4 + reg.
    const int orow = tm * 256 + wr * 128 + kg * 4;
    const int ocol = tn * 256 + wc * 64 + lr;
    if constexpr (OUT_BF16) {
        __bf16* C = (__bf16*)Cp + e * sC;
        #pragma unroll
        for (int mf = 0; mf < 8; ++mf)
            #pragma unroll
            for (int j = 0; j < 4; ++j) {
                const size_t base = (size_t)(orow + mf * 16 + j) * N + ocol;
                #pragma unroll
                for (int nf = 0; nf < 4; ++nf) {
                    float v = acc[mf][nf][j];
                    if (RELU) v = fmaxf(v, 0.f);
                    C[base + nf * 16] = (__bf16)v;
                }
            }
    } else {
        float* C = (float*)Cp + e * sC;
        #pragma unroll
        for (int mf = 0; mf < 8; ++mf)
            #pragma unroll
            for (int j = 0; j < 4; ++j) {
                const size_t base = (size_t)(orow + mf * 16 + j) * N + ocol;
                #pragma unroll
                for (int nf = 0; nf < 4; ++nf) {
                    float v = acc[mf][nf][j];
                    if (RELU) v = fmaxf(v, 0.f);
                    C[base + nf * 16] = v;
                }
            }
    }
}

// ---------------- fallback 128x128 kernel (tiers B-E) ----------------
template<int AMODE, int BMODE, bool RELU, bool OUT_BF16>
__global__ __launch_bounds__(256)
void gemm2(const void* __restrict__ Ap, const void* __restrict__ Bp,
           void* __restrict__ Cp, int N, int K, int tiles_m, int tiles_n,
           size_t sA, size_t sB, size_t sC)
{
    constexpr int LA = (AMODE == 0) ? BK : LSTR;
    constexpr int LB = (BMODE == 0) ? BK : LSTR;
    __shared__ __bf16 As[BM * LA];
    __shared__ __bf16 Bs[BN * LB];

    int bid = blockIdx.x;
    const int chunk = gridDim.x >> 3;
    bid = (bid & 7) * chunk + (bid >> 3);

    const int per_e = tiles_m * tiles_n;
    const int e  = bid / per_e;
    const int t  = bid - e * per_e;
    const int tn = t / tiles_m;
    const int tm = t - tn * tiles_m;

    const int tid = threadIdx.x;
    const int l   = tid & 63;
    const int wid = tid >> 6;
    const int wr  = wid >> 1, wc = wid & 1;
    const int lr  = l & 15;
    const int kg  = l >> 4;
    const int srow = tid >> 1;
    const int scol = (tid & 1) << 4;

    const __bf16* gA = nullptr; __bf16* lA = nullptr;
    const float*  pAf = nullptr; __bf16* aWr = nullptr;
    float4 A0, A1, A2, A3;
    if constexpr (AMODE == 0) {
        gA = (const __bf16*)Ap + e * sA
           + (size_t)(tm * BM + wid * 16 + (l >> 2)) * K + (l & 3) * 8;
        lA = As + wid * 512;
    } else {
        pAf = (const float*)Ap + e * sA + (size_t)(tm * BM + srow) * K + scol;
        aWr = As + srow * LA + scol;
        A0 = *(const float4*)(pAf);      A1 = *(const float4*)(pAf + 4);
        A2 = *(const float4*)(pAf + 8);  A3 = *(const float4*)(pAf + 12);
    }
    const __bf16* gB = nullptr; __bf16* lB = nullptr;
    const float*  pBf = nullptr; __bf16* bWr = nullptr;
    float4 B0, B1, B2, B3;
    if constexpr (BMODE == 0) {
        gB = (const __bf16*)Bp + e * sB
           + (size_t)(tn * BN + wid * 16 + (l >> 2)) * K + (l & 3) * 8;
        lB = Bs + wid * 512;
    } else {
        pBf = (const float*)Bp + e * sB + (size_t)(tn * BN + srow) * K + scol;
        bWr = Bs + srow * LB + scol;
        B0 = *(const float4*)(pBf);      B1 = *(const float4*)(pBf + 4);
        B2 = *(const float4*)(pBf + 8);  B3 = *(const float4*)(pBf + 12);
    }

    const __bf16* aRd = As + (wr * 64 + lr) * LA + kg * 8;
    const __bf16* bRd = Bs + (wc * 64 + lr) * LB + kg * 8;

    f32x4 acc[4][4];
    #pragma unroll
    for (int m = 0; m < 4; ++m)
        #pragma unroll
        for (int n = 0; n < 4; ++n)
            acc[m][n] = (f32x4){0.f, 0.f, 0.f, 0.f};

    const int NT = K / BK;
    for (int kt = 0; kt < NT; ++kt) {
        if (kt) __syncthreads();
        if constexpr (AMODE == 0) {
            gload16(gA, lA);
            gload16(gA + (size_t)64 * K, lA + 2048);
            gA += BK;
        } else {
            *(bf16x8*)(aWr)     = cvt8(A0, A1);
            *(bf16x8*)(aWr + 8) = cvt8(A2, A3);
        }
        if constexpr (BMODE == 0) {
            gload16(gB, lB);
            gload16(gB + (size_t)64 * K, lB + 2048);
            gB += BK;
        } else {
            *(bf16x8*)(bWr)     = cvt8(B0, B1);
            *(bf16x8*)(bWr + 8) = cvt8(B2, B3);
        }
        __syncthreads();

        if (kt + 1 < NT) {
            if constexpr (AMODE == 2) {
                pAf += BK;
                A0 = *(const float4*)(pAf);      A1 = *(const float4*)(pAf + 4);
                A2 = *(const float4*)(pAf + 8);  A3 = *(const float4*)(pAf + 12);
            }
            if constexpr (BMODE == 2) {
                pBf += BK;
                B0 = *(const float4*)(pBf);      B1 = *(const float4*)(pBf + 4);
                B2 = *(const float4*)(pBf + 8);  B3 = *(const float4*)(pBf + 12);
            }
        }

        bf16x8 af[4], bfr[4];
        #pragma unroll
        for (int m = 0; m < 4; ++m) af[m]  = *(const bf16x8*)(aRd + m * 16 * LA);
        #pragma unroll
        for (int n = 0; n < 4; ++n) bfr[n] = *(const bf16x8*)(bRd + n * 16 * LB);
        #pragma unroll
        for (int m = 0; m < 4; ++m)
            #pragma unroll
            for (int n = 0; n < 4; ++n)
                acc[m][n] = __builtin_amdgcn_mfma_f32_16x16x32_bf16(af[m], bfr[n], acc[m][n], 0, 0, 0);
    }

    const int orow = tm * BM + wr * 64 + kg * 4;
    const int ocol = tn * BN + wc * 64 + lr;
    if constexpr (OUT_BF16) {
        __bf16* C = (__bf16*)Cp + e * sC;
        #pragma unroll
        for (int m = 0; m < 4; ++m)
            #pragma unroll
            for (int j = 0; j < 4; ++j) {
                const size_t base = (size_t)(orow + m * 16 + j) * N + ocol;
                #pragma unroll
                for (int n = 0; n < 4; ++n) {
                    float v = acc[m][n][j];
                    if (RELU) v = fmaxf(v, 0.f);
                    C[base + n * 16] = (__bf16)v;
                }
            }
    } else {
        float* C = (float*)Cp + e * sC;
        #pragma unroll
        for (int m = 0; m < 4; ++m)
            #pragma unroll
            for (int j = 0; j < 4; ++j) {
                const size_t base = (size_t)(orow + m * 16 + j) * N + ocol;
                #pragma unroll
                for (int n = 0; n < 4; ++n) {
                    float v = acc[m][n][j];
                    if (RELU) v = fmaxf(v, 0.f);
                    C[base + n * 16] = v;
                }
            }
    }
}

extern "C" void kernel_launch(void* const* d_in, const int* in_sizes, int n_in,
                              void* d_out, int out_size, void* d_ws, size_t ws_size,
                              hipStream_t stream) {
    const float* x  = (const float*)d_in[0];   // [8, 2048, 1024]
    const float* w1 = (const float*)d_in[1];   // [8, 4096, 1024]
    const float* w2 = (const float*)d_in[2];   // [8, 1024, 4096]
    float* out = (float*)d_out;                // [8, 2048, 1024]

    const size_t SZ_F  = (size_t)EXPERTS * TOK * DH * sizeof(__bf16);  // 134.2 MB
    const size_t SZ_X  = (size_t)EXPERTS * TOK * DM * sizeof(__bf16);
    const size_t SZ_W1 = (size_t)EXPERTS * DH * DM * sizeof(__bf16);
    const size_t SZ_W2 = (size_t)EXPERTS * DM * DH * sizeof(__bf16);

    char* wsb = (char*)d_ws;
    __bf16* ffn1 = (__bf16*)wsb;

    const dim3 blk(256);
    const dim3 cgrid(2048);
    const int NX  = EXPERTS * TOK * DM / 8;
    const int NW1 = EXPERTS * DH * DM / 8;
    const int NW2 = EXPERTS * DM * DH / 8;

    const size_t eA1 = (size_t)TOK * DM, eB1 = (size_t)DH * DM, eC1 = (size_t)TOK * DH;
    const size_t eA2 = (size_t)TOK * DH, eB2 = (size_t)DM * DH, eC2 = (size_t)TOK * DM;

    if (ws_size >= SZ_F + SZ_X + SZ_W1 + SZ_W2) {
        // Tier A: fused cvt, then both GEMMs on the kk-split 8-phase kernel
        __bf16* xb  = (__bf16*)(wsb + SZ_F);
        __bf16* w1b = (__bf16*)(wsb + SZ_F + SZ_X);
        __bf16* w2b = (__bf16*)(wsb + SZ_F + SZ_X + SZ_W1);
        hipLaunchKernelGGL(cvt_all, cgrid, blk, 0, stream,
            x, w1, w2, xb, w1b, w2b, NX, NW1, NX + NW1 + NW2);
        const dim3 g1(EXPERTS * (TOK / 256) * (DH / 256));   // 1024
        const dim3 g2(EXPERTS * (TOK / 256) * (DM / 256));   // 256
        hipLaunchKernelGGL((gemm8<true, true>), g1, dim3(512), 0, stream,
            xb, w1b, ffn1, DH, DM, TOK / 256, DH / 256, eA1, eB1, eC1);
        hipLaunchKernelGGL((gemm8<false, false>), g2, dim3(512), 0, stream,
            ffn1, w2b, out, DM, DH, TOK / 256, DM / 256, eA2, eB2, eC2);
    } else if (ws_size >= SZ_F + SZ_X + SZ_W1) {
        __bf16* xb  = (__bf16*)(wsb + SZ_F);
        __bf16* w1b = (__bf16*)(wsb + SZ_F + SZ_X);
        hipLaunchKernelGGL(cvt_all, cgrid, blk, 0, stream,
            x, w1, w1, xb, w1b, w1b, NX, NW1, NX + NW1);
        const dim3 g1(EXPERTS * (TOK / 256) * (DH / 256));
        const dim3 g2(EXPERTS * (TOK / BM) * (DM / BN));
        hipLaunchKernelGGL((gemm8<true, true>), g1, dim3(512), 0, stream,
            xb, w1b, ffn1, DH, DM, TOK / 256, DH / 256, eA1, eB1, eC1);
        hipLaunchKernelGGL((gemm2<0, 2, false, false>), g2, blk, 0, stream,
            ffn1, w2, out, DM, DH, TOK / BM, DM / BN, eA2, eB2, eC2);
    } else if (ws_size >= SZ_F + SZ_W1) {
        __bf16* w1b = (__bf16*)(wsb + SZ_F);
        hipLaunchKernelGGL(cvt_all, cgrid, blk, 0, stream,
            w1, w1, w1, w1b, w1b, w1b, NW1, 0, NW1);
        const dim3 g1(EXPERTS * (TOK / BM) * (DH / BN));
        const dim3 g2(EXPERTS * (TOK / BM) * (DM / BN));
        hipLaunchKernelGGL((gemm2<2, 0, true, true>), g1, blk, 0, stream,
            x, w1b, ffn1, DH, DM, TOK / BM, DH / BN, eA1, eB1, eC1);
        hipLaunchKernelGGL((gemm2<0, 2, false, false>), g2, blk, 0, stream,
            ffn1, w2, out, DM, DH, TOK / BM, DM / BN, eA2, eB2, eC2);
    } else if (ws_size >= SZ_F) {
        const dim3 g1(EXPERTS * (TOK / BM) * (DH / BN));
        const dim3 g2(EXPERTS * (TOK / BM) * (DM / BN));
        hipLaunchKernelGGL((gemm2<2, 2, true, true>), g1, blk, 0, stream,
            x, w1, ffn1, DH, DM, TOK / BM, DH / BN, eA1, eB1, eC1);
        hipLaunchKernelGGL((gemm2<0, 2, false, false>), g2, blk, 0, stream,
            ffn1, w2, out, DM, DH, TOK / BM, DM / BN, eA2, eB2, eC2);
    } else {
        int rows = (int)((ws_size / ((size_t)DH * sizeof(__bf16))) / BM) * BM;
        if (rows <= 0) rows = BM;
        if (rows > TOK) rows = TOK;
        for (int e = 0; e < EXPERTS; ++e) {
            for (int r0 = 0; r0 < TOK; r0 += rows) {
                int mr = (TOK - r0 < rows) ? (TOK - r0) : rows;
                dim3 cg1((mr / BM) * (DH / BN));
                hipLaunchKernelGGL((gemm2<2, 2, true, true>), cg1, blk, 0, stream,
                    x + ((size_t)e * TOK + r0) * DM, w1 + (size_t)e * DH * DM, ffn1,
                    DH, DM, mr / BM, DH / BN, (size_t)0, (size_t)0, (size_t)0);
                dim3 cg2((mr / BM) * (DM / BN));
                hipLaunchKernelGGL((gemm2<0, 2, false, false>), cg2, blk, 0, stream,
                    ffn1, w2 + (size_t)e * DM * DH, out + ((size_t)e * TOK + r0) * DM,
                    DM, DH, mr / BM, DM / BN, (size_t)0, (size_t)0, (size_t)0);
            }
        }
    }
}